// Round 5
// baseline (140.177 us; speedup 1.0000x reference)
//
#include <hip/hip_runtime.h>
#include <math.h>

// OLE loss on MI355X — FUSED single kernel, R20.
// ||X_c||* = trace(sqrt(G_c)), G_c = X_c^T X_c (128x128).
// R20 changes vs R18 (77us dispatch; NS chain ~65us is 2.5x above its LDS
// throughput floor -> barrier/latency bound at 2 waves/SIMD):
//  NS iteration restructured 3 barriers -> 2:
//   (a) W=Z*Y AND preload ALL phase-(c) B-fragments of Y,Z into registers
//       (+64 VGPR). After barrier 1, LDS Yb/Zb are DEAD.
//   (b) M = kA*I - kB*W, clamp, hi/lo split, transposed store. BARRIER 1.
//   (c) Y'=M*Y, Z'=M*Z reading ONLY Mh/Ml from LDS (B-frags in regs) —
//       shorter ds_read->MFMA chain, reads 72->64/wave/iter.
//   (d) store Y'/Z' straight into Yb/Zb (dead since barrier 1). BARRIER 2.
//  Last iteration skips the Y-update entirely (only Z feeds the traces) —
//  numerically identical, -32 MFMA -8 stores on the chain.
// Correctness: every LDS location's readers/writers are separated by a
// barrier (B1: {a,b} | {c,d}; B2: {c,d} | next {a,b}).
// Kept: builders tree-sum Gall (R16; atomics were 16.4MB RMW), ballot list,
// 512t/8-wave/4x2-frag NS engine (R15/R18; 1024t collapses to VGPR=64 —
// R16/R17), flag dataflow. Lessons: R4 (hi/lo split), R8 (grid.sync ~50us),
// R11 (one flag/lane), R14 (NITER=7), R17 (bank conflicts NS-internal,
// negligible: 7.4K cy/block).

#define N_ROWS 8192
#define DIM    128
#define NCLS   64
#define NB_CE  64
#define NB_BLD 16
#define NITER  7
#define EPSN   2e-4f
#define LAMBDA_ 0.25f
#define DELTA_  1.0f
#define MAGIC  0x13579BDF   // != 0xAAAAAAAA poison, != 0

typedef __attribute__((ext_vector_type(8))) short s16x8;  // 8 bf16 = 4 VGPR
typedef __attribute__((ext_vector_type(4))) short s16x4;  // 4 bf16
typedef __attribute__((ext_vector_type(4))) float f32x4;

// Scaled-NS ladder: M_k = C1[k]*I - C2[k]*W, C1 = 1.5*sqrt(t), C2 = 0.5*t^1.5.
static __device__ const float NS_C1[NITER] =
  {2.554408f, 2.491084f, 2.189178f, 2.050122f, 1.686417f, 1.5f, 1.5f};
static __device__ const float NS_C2[NITER] =
  {2.469261f, 2.290137f, 1.554316f, 1.276543f, 0.710544f, 0.5f, 0.5f};

__device__ __forceinline__ unsigned short f2bf(float f) {   // RNE
  unsigned u = __float_as_uint(f);
  u = (u + 0x7FFFu + ((u >> 16) & 1u)) >> 16;
  return (unsigned short)u;
}
__device__ __forceinline__ float bf2f(unsigned short h) {
  return __uint_as_float(((unsigned)h) << 16);
}

// bf16 LDS: element (i,j) at short-index i*128 + (((j>>3)^(i&15))<<3) + (j&7)
__device__ __forceinline__ int swz_idx(int i, int j) {
  return i * 128 + (((j >> 3) ^ (i & 15)) << 3) + (j & 7);
}

__device__ __forceinline__ s16x8 load_frag(const short* buf, int row0,
                                           int kstep, int lane) {
  int m  = row0 + (lane & 15);
  int kg = kstep * 4 + (lane >> 4);
  return *(const s16x8*)(buf + m * 128 + ((kg ^ (m & 15)) << 3));
}

__device__ __forceinline__ void flag_set(int* p) {
  __threadfence();
  __hip_atomic_store(p, MAGIC, __ATOMIC_RELEASE, __HIP_MEMORY_SCOPE_AGENT);
}
__device__ __forceinline__ void flag_wait(const int* p) {
  while (__hip_atomic_load(p, __ATOMIC_ACQUIRE, __HIP_MEMORY_SCOPE_AGENT) != MAGIC)
    __builtin_amdgcn_s_sleep(8);
}

// ---------------------------------------------------------------------------
// Fused kernel: 145 blocks x 512 threads (8 waves, 2/SIMD).
//  0..63   : ballot list -> LDS-staged Gram -> store G_c -> gramdone
//            -> NS(G_c, reg anchor) -> nuc[c] -> nflag
//  64      : wait gallf[16] -> load Gall -> NS -> wait nflag/ceflag -> out
//  65..128 : CE (512 waves total) -> cepart -> ceflag
//  129..144: wait gramdone[64] -> tree-sum G_c slice -> Gall -> gallf
// ---------------------------------------------------------------------------
__global__ __launch_bounds__(512, 1) void ole_fused(const float* __restrict__ feat,
                                                    const int* __restrict__ y,
                                                    const float* __restrict__ logits,
                                                    float* __restrict__ G,
                                                    float* __restrict__ nuc,
                                                    float* __restrict__ cepart,
                                                    int* __restrict__ flags,
                                                    float* __restrict__ out) {
  int* gramdone = flags;            // 64
  int* gallf    = flags + 64;       // 16
  int* nflag    = flags + 80;       // 64
  int* ceflag   = flags + 144;      // 64

  __shared__ __align__(16) short Yb[DIM * DIM];
  __shared__ __align__(16) short Mh[DIM * DIM];
  __shared__ __align__(16) short Ml[DIM * DIM];
  __shared__ __align__(16) short Zb[DIM * DIM];
  __shared__ int cnt;

  const int bid  = blockIdx.x;
  const int tid  = threadIdx.x;
  const int lane = tid & 63;
  const int quad = lane >> 4;
  const int wv   = tid >> 6;    // 0..7

  float* Gall = G + (size_t)NCLS * DIM * DIM;

  // ---------------- CE blocks (65..128): 512 waves total ----------------
  if (bid > NCLS && bid <= NCLS + NB_CE) {
    const int gwave = (bid - NCLS - 1) * 8 + wv;
    float acc = 0.f;
    for (int row = gwave; row < N_ROWS; row += 512) {
      float v = logits[row * NCLS + lane];
      float mx = v;
      for (int off = 32; off > 0; off >>= 1) mx = fmaxf(mx, __shfl_xor(mx, off, 64));
      float e = expf(v - mx);
      for (int off = 32; off > 0; off >>= 1) e += __shfl_xor(e, off, 64);
      if (lane == 0) {
        int t = y[row];
        acc += (mx + logf(e)) - logits[row * NCLS + t];
      }
    }
    if (lane == 0) cepart[gwave] = acc;
    __syncthreads();
    if (tid == 0) flag_set(&ceflag[bid - NCLS - 1]);
    return;
  }

  // ---------------- builder blocks (129..144) ----------------
  if (bid > NCLS + NB_CE) {
    const int gb = bid - (NCLS + 1 + NB_CE);        // 0..15
    if (tid < NCLS) flag_wait(&gramdone[tid]);      // one flag per lane
    __syncthreads();
    if (tid < 256) {
      const int idx4 = gb * 256 + tid;              // 16 x 256 = 4096 float4s
      const float4* G4 = (const float4*)G;
      float4 s = make_float4(0.f, 0.f, 0.f, 0.f);
#pragma unroll 8
      for (int c = 0; c < NCLS; ++c) {
        float4 v = G4[(size_t)c * (DIM * DIM / 4) + idx4];
        s.x += v.x; s.y += v.y; s.z += v.z; s.w += v.w;
      }
      ((float4*)Gall)[idx4] = s;
    }
    __syncthreads();
    if (tid == 0) flag_set(&gallf[gb]);
    return;
  }

  // ====================== gram + NS blocks (0..64) ======================
  // 512 threads = 16x32 grid; thread owns 8x4 patch (i0..i0+7, j0..j0+3)
  const int ti = tid >> 5, tj = tid & 31;
  const int i0 = ti * 8,  j0 = tj * 4;

  float tpart = 0.f, fpart = 0.f;
  float4 gs[8];        // block 64 only: Gall slice (NS anchor)
  float  accg[8][4];   // class only: fp32 G_c patch (NS anchor)

  if (bid < NCLS) {
    // ---- ballot-compacted row list (one lane-0 atomicAdd per 64 rows) ----
    int* list = (int*)Yb;                       // up to 8192 ints (= Yb)
    if (tid == 0) cnt = 0;
    __syncthreads();
#pragma unroll
    for (int t = 0; t < 16; ++t) {
      int row = t * 512 + tid;
      bool hit = (y[row] == bid);
      unsigned long long m = __ballot(hit);
      int base = 0;
      if (lane == 0 && m) base = atomicAdd(&cnt, __popcll(m));
      base = __shfl(base, 0, 64);
      if (hit) {
        int pre = __popcll(m & ((1ull << lane) - 1ull));
        list[base + pre] = row;
      }
    }
    __syncthreads();
    const int n = cnt;

    float (*xs)[DIM] = (float (*)[DIM])Mh;      // 16x128 f32 = 8 KB (in Mh)

#pragma unroll
    for (int a = 0; a < 8; ++a)
#pragma unroll
      for (int b = 0; b < 4; ++b) accg[a][b] = 0.f;

    for (int base = 0; base < n; base += 16) {
      int li = base + ti;                       // ti doubles as load-row
      float4 v = make_float4(0.f, 0.f, 0.f, 0.f);
      if (li < n) v = *(const float4*)(feat + (size_t)list[li] * DIM + j0);
      __syncthreads();                          // prev chunk's reads done
      *(float4*)(&xs[ti][j0]) = v;
      __syncthreads();
#pragma unroll
      for (int rw = 0; rw < 16; ++rw) {
        float xi[8], xj[4];
#pragma unroll
        for (int a = 0; a < 8; ++a) xi[a] = xs[rw][i0 + a];
#pragma unroll
        for (int b = 0; b < 4; ++b) xj[b] = xs[rw][j0 + b];
#pragma unroll
        for (int a = 0; a < 8; ++a)
#pragma unroll
          for (int b = 0; b < 4; ++b) accg[a][b] = fmaf(xi[a], xj[b], accg[a][b]);
      }
    }

    // stats + store G_c (plain stores; flag pattern proven by cepart/nuc)
    float* Gc = G + (size_t)bid * DIM * DIM;
#pragma unroll
    for (int a = 0; a < 8; ++a) {
      float4 row;
      float* rp = (float*)&row;
#pragma unroll
      for (int b = 0; b < 4; ++b) {
        float g = accg[a][b];
        rp[b] = g;
        fpart += g * g;
        if (i0 + a == j0 + b) tpart += g;
      }
      *(float4*)(Gc + (size_t)(i0 + a) * DIM + j0) = row;
    }
    __syncthreads();   // all threads' stores drained (vmcnt0 at barrier)
    if (tid == 0) flag_set(&gramdone[bid]);
    // list (Yb) / xs (Mh) dead from here.
  } else {
    // ---- block 64: wait for builders, load Gall ----
    if (tid < NB_BLD) flag_wait(&gallf[tid]);   // one flag per lane
    __syncthreads();
    const float4* Gm4 = (const float4*)Gall;
#pragma unroll
    for (int t = 0; t < 8; ++t) {
      int idx4 = tid + 512 * t;
      float4 v = Gm4[idx4];
      gs[t] = v;
      fpart += v.x * v.x + v.y * v.y + v.z * v.z + v.w * v.w;
      int flat = idx4 * 4, i = flat >> 7, jj = flat & 127;
      if (jj <= i && i < jj + 4) tpart += ((const float*)&v)[i - jj];
    }
  }

  // ---- reduce trace / fro2 across 8 waves ----
  for (int off = 32; off > 0; off >>= 1) {
    tpart += __shfl_down(tpart, off, 64);
    fpart += __shfl_down(fpart, off, 64);
  }
  float* redf = (float*)Zb;           // Zb not yet initialized
  if (lane == 0) { redf[wv] = tpart; redf[8 + wv] = fpart; }
  __syncthreads();
  float trace = 0.f, fro2 = 0.f;
#pragma unroll
  for (int w = 0; w < 8; ++w) { trace += redf[w]; fro2 += redf[8 + w]; }
  __syncthreads();                    // redf reads done -> Zb reusable

  float s = sqrtf(fro2);
  if (s < 1e-12f) s = 1.f;
  const float invs = 1.f / s;
  const float eps  = EPSN * trace * invs;

  // ---- init: Y0 = G/s + eps*I (single bf16), Z0 = I ----
  if (bid < NCLS) {
#pragma unroll
    for (int a = 0; a < 8; ++a) {
      int i = i0 + a;
      s16x4 vh;
#pragma unroll
      for (int b = 0; b < 4; ++b) {
        float x = accg[a][b] * invs + ((i == j0 + b) ? eps : 0.f);
        vh[b] = (short)f2bf(x);
      }
      *(s16x4*)(Yb + swz_idx(i, j0)) = vh;
    }
  } else {
#pragma unroll
    for (int t = 0; t < 8; ++t) {
      int idx4 = tid + 512 * t;
      int flat = idx4 * 4, i = flat >> 7, jj = flat & 127;
      s16x4 vh;
#pragma unroll
      for (int e = 0; e < 4; ++e) {
        float x = ((const float*)&gs[t])[e] * invs + ((i == jj + e) ? eps : 0.f);
        vh[e] = (short)f2bf(x);
      }
      *(s16x4*)(Yb + swz_idx(i, jj)) = vh;
    }
  }
  for (int grp = tid; grp < DIM * 16; grp += 512) {
    int i = grp >> 4, g = grp & 15;
    s16x8 v = (s16x8)0;
    if ((i >> 3) == g) v[i & 7] = (short)0x3F80;   // 1.0 bf16
    *(s16x8*)(Zb + i * 128 + ((g ^ (i & 15)) << 3)) = v;
  }
  __syncthreads();

  // 8 waves: 2x4 wave grid, each wave owns a 64x32 output tile (4x2 frags)
  const int wr = wv >> 2;     // 0..1 -> tile-rows 4*wr..4*wr+3
  const int wc = wv & 3;      // 0..3 -> tile-cols 2*wc..2*wc+1

  for (int it = 0; it < NITER; ++it) {
    const float kA = NS_C1[it];
    const float kB = NS_C2[it];
    const bool upd_y = (it != NITER - 1);   // last iter: Y' dead (traces use Z)

    // --- (a) W = Z*Y; preload ALL phase-(c) B-frags of Y,Z into registers ---
    f32x4 acc[4][2];
    s16x8 bY[4][2], bZ[4][2];
#pragma unroll
    for (int r = 0; r < 4; ++r)
#pragma unroll
      for (int c2 = 0; c2 < 2; ++c2) acc[r][c2] = (f32x4)0.f;
#pragma unroll
    for (int ks = 0; ks < 4; ++ks) {
      s16x8 a[4];
#pragma unroll
      for (int r = 0; r < 4; ++r) a[r] = load_frag(Zb, (4 * wr + r) * 16, ks, lane);
#pragma unroll
      for (int c2 = 0; c2 < 2; ++c2) {
        bY[ks][c2] = load_frag(Yb, (2 * wc + c2) * 16, ks, lane);
        bZ[ks][c2] = load_frag(Zb, (2 * wc + c2) * 16, ks, lane);
      }
#pragma unroll
      for (int r = 0; r < 4; ++r)
#pragma unroll
        for (int c2 = 0; c2 < 2; ++c2)
          acc[r][c2] = __builtin_amdgcn_mfma_f32_16x16x32_bf16(a[r], bY[ks][c2], acc[r][c2], 0, 0, 0);
    }
    // --- (b) M = kA*I - kB*W, clamp, hi/lo split, transposed store ---
#pragma unroll
    for (int r = 0; r < 4; ++r) {
      int ibase = (4 * wr + r) * 16 + quad * 4;
      int cg    = ibase >> 3;
#pragma unroll
      for (int c2 = 0; c2 < 2; ++c2) {
        int jg  = (2 * wc + c2) * 16 + (lane & 15);
        int idx = jg * 128 + ((cg ^ (jg & 15)) << 3) + (ibase & 7);
        s16x4 vh, vl;
#pragma unroll
        for (int e = 0; e < 4; ++e) {
          float mv = -kB * acc[r][c2][e] + ((ibase + e == jg) ? kA : 0.f);
          mv = fminf(fmaxf(mv, -4.f), 4.f);
          unsigned short hh = f2bf(mv);
          vh[e] = (short)hh;
          vl[e] = (short)f2bf(mv - bf2f(hh));
        }
        *(s16x4*)(Mh + idx) = vh;
        *(s16x4*)(Ml + idx) = vl;
      }
    }
    __syncthreads();   // BARRIER 1: M visible; Yb/Zb dead (B-frags in regs)

    // --- (c) Y' = M*Y, Z' = M*Z — LDS reads are Mh/Ml ONLY ---
    f32x4 ay[4][2], az[4][2];
#pragma unroll
    for (int r = 0; r < 4; ++r)
#pragma unroll
      for (int c2 = 0; c2 < 2; ++c2) { ay[r][c2] = (f32x4)0.f; az[r][c2] = (f32x4)0.f; }
#pragma unroll
    for (int ks = 0; ks < 4; ++ks) {
      s16x8 aMh[4], aMl[4];
#pragma unroll
      for (int r = 0; r < 4; ++r) {
        int rb = (4 * wr + r) * 16;
        aMh[r] = load_frag(Mh, rb, ks, lane);
        aMl[r] = load_frag(Ml, rb, ks, lane);
      }
#pragma unroll
      for (int r = 0; r < 4; ++r)
#pragma unroll
        for (int c2 = 0; c2 < 2; ++c2) {
          az[r][c2] = __builtin_amdgcn_mfma_f32_16x16x32_bf16(aMh[r], bZ[ks][c2], az[r][c2], 0, 0, 0);
          az[r][c2] = __builtin_amdgcn_mfma_f32_16x16x32_bf16(aMl[r], bZ[ks][c2], az[r][c2], 0, 0, 0);
          if (upd_y) {
            ay[r][c2] = __builtin_amdgcn_mfma_f32_16x16x32_bf16(aMh[r], bY[ks][c2], ay[r][c2], 0, 0, 0);
            ay[r][c2] = __builtin_amdgcn_mfma_f32_16x16x32_bf16(aMl[r], bY[ks][c2], ay[r][c2], 0, 0, 0);
          }
        }
    }

    // --- (d) store Z' (and Y' unless last iter), transposed, into dead bufs ---
#pragma unroll
    for (int r = 0; r < 4; ++r) {
      int ibase = (4 * wr + r) * 16 + quad * 4;
      int cg    = ibase >> 3;
#pragma unroll
      for (int c2 = 0; c2 < 2; ++c2) {
        int jg  = (2 * wc + c2) * 16 + (lane & 15);
        int idx = jg * 128 + ((cg ^ (jg & 15)) << 3) + (ibase & 7);
        s16x4 vy, vz;
#pragma unroll
        for (int e = 0; e < 4; ++e) {
          vy[e] = (short)f2bf(ay[r][c2][e]);
          vz[e] = (short)f2bf(az[r][c2][e]);
        }
        *(s16x4*)(Zb + idx) = vz;
        if (upd_y) *(s16x4*)(Yb + idx) = vy;
      }
    }
    __syncthreads();   // BARRIER 2: Y'/Z' visible for next (a) / traces
  }

  // ---- traces: tr(GZ) (fp32 anchor in regs), tr(Z), tr(Z^3) ----
  float t_gz = 0.f, t_z = 0.f, t_z3 = 0.f;
  if (bid < NCLS) {
#pragma unroll
    for (int a = 0; a < 8; ++a) {
      s16x4 zv = *(const s16x4*)(Zb + swz_idx(i0 + a, j0));
#pragma unroll
      for (int b = 0; b < 4; ++b) t_gz += accg[a][b] * bf2f((unsigned short)zv[b]);
    }
  } else {
#pragma unroll
    for (int t = 0; t < 8; ++t) {
      int idx4 = tid + 512 * t;
      int flat = idx4 * 4, i = flat >> 7, jj = flat & 127;
      s16x4 zv = *(const s16x4*)(Zb + swz_idx(i, jj));
#pragma unroll
      for (int e = 0; e < 4; ++e) t_gz += ((const float*)&gs[t])[e] * bf2f((unsigned short)zv[e]);
    }
  }
  if (tid < DIM) t_z = bf2f((unsigned short)Zb[swz_idx(tid, tid)]);

  {  // U = Z*Z tile-wise; tr(Z^3) = sum U_ij * Z_ji
    f32x4 u[4][2];
#pragma unroll
    for (int r = 0; r < 4; ++r)
#pragma unroll
      for (int c2 = 0; c2 < 2; ++c2) u[r][c2] = (f32x4)0.f;
#pragma unroll
    for (int ks = 0; ks < 4; ++ks) {
      s16x8 a[4], b[2];
#pragma unroll
      for (int r = 0; r < 4; ++r) a[r] = load_frag(Zb, (4 * wr + r) * 16, ks, lane);
#pragma unroll
      for (int c2 = 0; c2 < 2; ++c2) b[c2] = load_frag(Zb, (2 * wc + c2) * 16, ks, lane);
#pragma unroll
      for (int r = 0; r < 4; ++r)
#pragma unroll
        for (int c2 = 0; c2 < 2; ++c2)
          u[r][c2] = __builtin_amdgcn_mfma_f32_16x16x32_bf16(a[r], b[c2], u[r][c2], 0, 0, 0);
    }
#pragma unroll
    for (int r = 0; r < 4; ++r) {
      int ibase = (4 * wr + r) * 16 + quad * 4;
      int cg    = ibase >> 3;
#pragma unroll
      for (int c2 = 0; c2 < 2; ++c2) {
        int jg  = (2 * wc + c2) * 16 + (lane & 15);
        int idx = jg * 128 + ((cg ^ (jg & 15)) << 3) + (ibase & 7);
        s16x4 zt = *(const s16x4*)(Zb + idx);
#pragma unroll
        for (int e = 0; e < 4; ++e) t_z3 += u[r][c2][e] * bf2f((unsigned short)zt[e]);
      }
    }
  }

  for (int off = 32; off > 0; off >>= 1) {
    t_gz += __shfl_down(t_gz, off, 64);
    t_z  += __shfl_down(t_z,  off, 64);
    t_z3 += __shfl_down(t_z3, off, 64);
  }
  __syncthreads();
  float* red = (float*)Mh;             // Mh dead after last iter
  if (lane == 0) { red[wv] = t_gz; red[8 + wv] = t_z; red[16 + wv] = t_z3; }
  __syncthreads();

  float nuc_own = 0.f;
  if (tid == 0) {
    float gz = 0.f, z1 = 0.f, z3 = 0.f;
#pragma unroll
    for (int w = 0; w < 8; ++w) { gz += red[w]; z1 += red[8 + w]; z3 += red[16 + w]; }
    float trsq = gz * invs + 0.5f * eps * z1 - 0.125f * eps * eps * z3;
    nuc_own = sqrtf(s) * trsq;
    nuc[bid] = nuc_own;
  }

  if (bid < NCLS) {
    if (tid == 0) flag_set(&nflag[bid]);
    return;
  }

  // ======== block 64: final combine (parallel poll, one flag/lane) ========
  if (tid < NCLS)          flag_wait(&nflag[tid]);
  else if (tid < 2 * NCLS) flag_wait(&ceflag[tid - NCLS]);
  __syncthreads();

  float ce2 = cepart[tid];                       // 512 entries, 512 threads
  float vmx = (tid < NCLS) ? fmaxf(nuc[tid], DELTA_) : 0.f;
  for (int off = 32; off > 0; off >>= 1) {
    vmx += __shfl_down(vmx, off, 64);
    ce2 += __shfl_down(ce2, off, 64);
  }
  if (lane == 0) { red[wv] = vmx; red[8 + wv] = ce2; }
  __syncthreads();
  if (tid == 0) {
    float vs = 0.f, cs = 0.f;
#pragma unroll
    for (int w = 0; w < 8; ++w) { vs += red[w]; cs += red[8 + w]; }
    float ole = (vs - nuc_own) * (LAMBDA_ / (float)N_ROWS);
    out[0] = ole + cs / (float)N_ROWS;
  }
}

extern "C" void kernel_launch(void* const* d_in, const int* in_sizes, int n_in,
                              void* d_out, int out_size, void* d_ws, size_t ws_size,
                              hipStream_t stream) {
  const float* logits = (const float*)d_in[0];   // out  [8192,64]
  const float* feat   = (const float*)d_in[1];   // feat [8192,128]
  const int*   yp     = (const int*)d_in[2];     // y    [8192]

  int*   flags  = (int*)d_ws;                    // 256 ints (208 used)
  float* nuc    = (float*)d_ws + 256;            // 68
  float* cepart = nuc + 68;                      // 512
  float* G      = cepart + 512;                  // 65 x 16384 (Gall = idx 64)

  // Zero the flag region (workspace is poisoned each run; keeps flag
  // semantics independent of harness re-poison timing). Graph-capture-safe.
  hipMemsetAsync(d_ws, 0, 256 * sizeof(int), stream);

  ole_fused<<<NCLS + 1 + NB_CE + NB_BLD, 512, 0, stream>>>(
      feat, yp, logits, G, nuc, cepart, flags, (float*)d_out);
}

// Round 6
// 128.584 us; speedup vs baseline: 1.0902x; 1.0902x over previous
//
#include <hip/hip_runtime.h>
#include <math.h>

// OLE loss on MI355X — FUSED single kernel, R21.
// ||X_c||* = trace(sqrt(G_c)), G_c = X_c^T X_c (128x128).
// R21 = R18's proven engine (77us; 512t/8-wave/4x2-frag, 3-barrier NS) with
// the chain shortened ARITHMETICALLY:
//  1. NITER 7 -> 6: R14's scalar trajectory of the ladder map over the
//     guaranteed spectrum shows |w-1| <= 1e-5 by k6 (k7 polished converged
//     modes). Loss-level error ~6e-6 — sub-tolerance. Saves ~9.3us.
//  2. Last iteration skips the Y-update (ay MFMAs + Y stores): traces use
//     only Z. Numerically identical. (The one valid piece of R20.)
// R20 post-mortem (98us, WRITE_SIZE 4.2->11MB): preloading bY/bZ frags into
// registers spilled to scratch — allocator stays pinned at VGPR=128 and
// spills rather than allocating (3rd confirmation after R16/R17). Register
// caching across barriers is OFF THE TABLE; LDS-read structure stays R18.
// Kept: builders tree-sum Gall (R16; atomics = 16.4MB RMW drain), ballot
// list, flag dataflow. Lessons: R4 (M hi/lo split), R8 (grid.sync ~50us),
// R11 (one flag/lane), R17 (bank conflicts NS-internal ~3us, minor).

#define N_ROWS 8192
#define DIM    128
#define NCLS   64
#define NB_CE  64
#define NB_BLD 16
#define NITER  6
#define EPSN   2e-4f
#define LAMBDA_ 0.25f
#define DELTA_  1.0f
#define MAGIC  0x13579BDF   // != 0xAAAAAAAA poison, != 0

typedef __attribute__((ext_vector_type(8))) short s16x8;  // 8 bf16 = 4 VGPR
typedef __attribute__((ext_vector_type(4))) short s16x4;  // 4 bf16
typedef __attribute__((ext_vector_type(4))) float f32x4;

// Scaled-NS ladder: M_k = C1[k]*I - C2[k]*W, C1 = 1.5*sqrt(t), C2 = 0.5*t^1.5.
// t-schedule {2.9, 2.758, 2.13, 1.868, 1.264, 1}; |w-1|<=1e-5 after step 6.
static __device__ const float NS_C1[NITER] =
  {2.554408f, 2.491084f, 2.189178f, 2.050122f, 1.686417f, 1.5f};
static __device__ const float NS_C2[NITER] =
  {2.469261f, 2.290137f, 1.554316f, 1.276543f, 0.710544f, 0.5f};

__device__ __forceinline__ unsigned short f2bf(float f) {   // RNE
  unsigned u = __float_as_uint(f);
  u = (u + 0x7FFFu + ((u >> 16) & 1u)) >> 16;
  return (unsigned short)u;
}
__device__ __forceinline__ float bf2f(unsigned short h) {
  return __uint_as_float(((unsigned)h) << 16);
}

// bf16 LDS: element (i,j) at short-index i*128 + (((j>>3)^(i&15))<<3) + (j&7)
__device__ __forceinline__ int swz_idx(int i, int j) {
  return i * 128 + (((j >> 3) ^ (i & 15)) << 3) + (j & 7);
}

__device__ __forceinline__ s16x8 load_frag(const short* buf, int row0,
                                           int kstep, int lane) {
  int m  = row0 + (lane & 15);
  int kg = kstep * 4 + (lane >> 4);
  return *(const s16x8*)(buf + m * 128 + ((kg ^ (m & 15)) << 3));
}

__device__ __forceinline__ void flag_set(int* p) {
  __threadfence();
  __hip_atomic_store(p, MAGIC, __ATOMIC_RELEASE, __HIP_MEMORY_SCOPE_AGENT);
}
__device__ __forceinline__ void flag_wait(const int* p) {
  while (__hip_atomic_load(p, __ATOMIC_ACQUIRE, __HIP_MEMORY_SCOPE_AGENT) != MAGIC)
    __builtin_amdgcn_s_sleep(8);
}

// ---------------------------------------------------------------------------
// Fused kernel: 145 blocks x 512 threads (8 waves, 2/SIMD, VGPR 128).
//  0..63   : ballot list -> LDS-staged Gram -> store G_c -> gramdone
//            -> NS(G_c, reg anchor) -> nuc[c] -> nflag
//  64      : wait gallf[16] -> load Gall -> NS -> wait nflag/ceflag -> out
//  65..128 : CE (512 waves total) -> cepart -> ceflag
//  129..144: wait gramdone[64] -> tree-sum G_c slice -> Gall -> gallf
// ---------------------------------------------------------------------------
__global__ __launch_bounds__(512, 1) void ole_fused(const float* __restrict__ feat,
                                                    const int* __restrict__ y,
                                                    const float* __restrict__ logits,
                                                    float* __restrict__ G,
                                                    float* __restrict__ nuc,
                                                    float* __restrict__ cepart,
                                                    int* __restrict__ flags,
                                                    float* __restrict__ out) {
  int* gramdone = flags;            // 64
  int* gallf    = flags + 64;       // 16
  int* nflag    = flags + 80;       // 64
  int* ceflag   = flags + 144;      // 64

  __shared__ __align__(16) short Yb[DIM * DIM];
  __shared__ __align__(16) short Mh[DIM * DIM];
  __shared__ __align__(16) short Ml[DIM * DIM];
  __shared__ __align__(16) short Zb[DIM * DIM];
  __shared__ int cnt;

  const int bid  = blockIdx.x;
  const int tid  = threadIdx.x;
  const int lane = tid & 63;
  const int quad = lane >> 4;
  const int wv   = tid >> 6;    // 0..7

  float* Gall = G + (size_t)NCLS * DIM * DIM;

  // ---------------- CE blocks (65..128): 512 waves total ----------------
  if (bid > NCLS && bid <= NCLS + NB_CE) {
    const int gwave = (bid - NCLS - 1) * 8 + wv;
    float acc = 0.f;
    for (int row = gwave; row < N_ROWS; row += 512) {
      float v = logits[row * NCLS + lane];
      float mx = v;
      for (int off = 32; off > 0; off >>= 1) mx = fmaxf(mx, __shfl_xor(mx, off, 64));
      float e = expf(v - mx);
      for (int off = 32; off > 0; off >>= 1) e += __shfl_xor(e, off, 64);
      if (lane == 0) {
        int t = y[row];
        acc += (mx + logf(e)) - logits[row * NCLS + t];
      }
    }
    if (lane == 0) cepart[gwave] = acc;
    __syncthreads();
    if (tid == 0) flag_set(&ceflag[bid - NCLS - 1]);
    return;
  }

  // ---------------- builder blocks (129..144) ----------------
  if (bid > NCLS + NB_CE) {
    const int gb = bid - (NCLS + 1 + NB_CE);        // 0..15
    if (tid < NCLS) flag_wait(&gramdone[tid]);      // one flag per lane
    __syncthreads();
    if (tid < 256) {
      const int idx4 = gb * 256 + tid;              // 16 x 256 = 4096 float4s
      const float4* G4 = (const float4*)G;
      float4 s = make_float4(0.f, 0.f, 0.f, 0.f);
#pragma unroll 8
      for (int c = 0; c < NCLS; ++c) {
        float4 v = G4[(size_t)c * (DIM * DIM / 4) + idx4];
        s.x += v.x; s.y += v.y; s.z += v.z; s.w += v.w;
      }
      ((float4*)Gall)[idx4] = s;
    }
    __syncthreads();
    if (tid == 0) flag_set(&gallf[gb]);
    return;
  }

  // ====================== gram + NS blocks (0..64) ======================
  // 512 threads = 16x32 grid; thread owns 8x4 patch (i0..i0+7, j0..j0+3)
  const int ti = tid >> 5, tj = tid & 31;
  const int i0 = ti * 8,  j0 = tj * 4;

  float tpart = 0.f, fpart = 0.f;
  float4 gs[8];        // block 64 only: Gall slice (NS anchor)
  float  accg[8][4];   // class only: fp32 G_c patch (NS anchor)

  if (bid < NCLS) {
    // ---- ballot-compacted row list (one lane-0 atomicAdd per 64 rows) ----
    int* list = (int*)Yb;                       // up to 8192 ints (= Yb)
    if (tid == 0) cnt = 0;
    __syncthreads();
#pragma unroll
    for (int t = 0; t < 16; ++t) {
      int row = t * 512 + tid;
      bool hit = (y[row] == bid);
      unsigned long long m = __ballot(hit);
      int base = 0;
      if (lane == 0 && m) base = atomicAdd(&cnt, __popcll(m));
      base = __shfl(base, 0, 64);
      if (hit) {
        int pre = __popcll(m & ((1ull << lane) - 1ull));
        list[base + pre] = row;
      }
    }
    __syncthreads();
    const int n = cnt;

    float (*xs)[DIM] = (float (*)[DIM])Mh;      // 16x128 f32 = 8 KB (in Mh)

#pragma unroll
    for (int a = 0; a < 8; ++a)
#pragma unroll
      for (int b = 0; b < 4; ++b) accg[a][b] = 0.f;

    for (int base = 0; base < n; base += 16) {
      int li = base + ti;                       // ti doubles as load-row
      float4 v = make_float4(0.f, 0.f, 0.f, 0.f);
      if (li < n) v = *(const float4*)(feat + (size_t)list[li] * DIM + j0);
      __syncthreads();                          // prev chunk's reads done
      *(float4*)(&xs[ti][j0]) = v;
      __syncthreads();
#pragma unroll
      for (int rw = 0; rw < 16; ++rw) {
        float xi[8], xj[4];
#pragma unroll
        for (int a = 0; a < 8; ++a) xi[a] = xs[rw][i0 + a];
#pragma unroll
        for (int b = 0; b < 4; ++b) xj[b] = xs[rw][j0 + b];
#pragma unroll
        for (int a = 0; a < 8; ++a)
#pragma unroll
          for (int b = 0; b < 4; ++b) accg[a][b] = fmaf(xi[a], xj[b], accg[a][b]);
      }
    }

    // stats + store G_c (plain stores; flag pattern proven by cepart/nuc)
    float* Gc = G + (size_t)bid * DIM * DIM;
#pragma unroll
    for (int a = 0; a < 8; ++a) {
      float4 row;
      float* rp = (float*)&row;
#pragma unroll
      for (int b = 0; b < 4; ++b) {
        float g = accg[a][b];
        rp[b] = g;
        fpart += g * g;
        if (i0 + a == j0 + b) tpart += g;
      }
      *(float4*)(Gc + (size_t)(i0 + a) * DIM + j0) = row;
    }
    __syncthreads();   // all threads' stores drained (vmcnt0 at barrier)
    if (tid == 0) flag_set(&gramdone[bid]);
    // list (Yb) / xs (Mh) dead from here.
  } else {
    // ---- block 64: wait for builders, load Gall ----
    if (tid < NB_BLD) flag_wait(&gallf[tid]);   // one flag per lane
    __syncthreads();
    const float4* Gm4 = (const float4*)Gall;
#pragma unroll
    for (int t = 0; t < 8; ++t) {
      int idx4 = tid + 512 * t;
      float4 v = Gm4[idx4];
      gs[t] = v;
      fpart += v.x * v.x + v.y * v.y + v.z * v.z + v.w * v.w;
      int flat = idx4 * 4, i = flat >> 7, jj = flat & 127;
      if (jj <= i && i < jj + 4) tpart += ((const float*)&v)[i - jj];
    }
  }

  // ---- reduce trace / fro2 across 8 waves ----
  for (int off = 32; off > 0; off >>= 1) {
    tpart += __shfl_down(tpart, off, 64);
    fpart += __shfl_down(fpart, off, 64);
  }
  float* redf = (float*)Zb;           // Zb not yet initialized
  if (lane == 0) { redf[wv] = tpart; redf[8 + wv] = fpart; }
  __syncthreads();
  float trace = 0.f, fro2 = 0.f;
#pragma unroll
  for (int w = 0; w < 8; ++w) { trace += redf[w]; fro2 += redf[8 + w]; }
  __syncthreads();                    // redf reads done -> Zb reusable

  float s = sqrtf(fro2);
  if (s < 1e-12f) s = 1.f;
  const float invs = 1.f / s;
  const float eps  = EPSN * trace * invs;

  // ---- init: Y0 = G/s + eps*I (single bf16), Z0 = I ----
  if (bid < NCLS) {
#pragma unroll
    for (int a = 0; a < 8; ++a) {
      int i = i0 + a;
      s16x4 vh;
#pragma unroll
      for (int b = 0; b < 4; ++b) {
        float x = accg[a][b] * invs + ((i == j0 + b) ? eps : 0.f);
        vh[b] = (short)f2bf(x);
      }
      *(s16x4*)(Yb + swz_idx(i, j0)) = vh;
    }
  } else {
#pragma unroll
    for (int t = 0; t < 8; ++t) {
      int idx4 = tid + 512 * t;
      int flat = idx4 * 4, i = flat >> 7, jj = flat & 127;
      s16x4 vh;
#pragma unroll
      for (int e = 0; e < 4; ++e) {
        float x = ((const float*)&gs[t])[e] * invs + ((i == jj + e) ? eps : 0.f);
        vh[e] = (short)f2bf(x);
      }
      *(s16x4*)(Yb + swz_idx(i, jj)) = vh;
    }
  }
  for (int grp = tid; grp < DIM * 16; grp += 512) {
    int i = grp >> 4, g = grp & 15;
    s16x8 v = (s16x8)0;
    if ((i >> 3) == g) v[i & 7] = (short)0x3F80;   // 1.0 bf16
    *(s16x8*)(Zb + i * 128 + ((g ^ (i & 15)) << 3)) = v;
  }
  __syncthreads();

  // 8 waves: 2x4 wave grid, each wave owns a 64x32 output tile (4x2 frags)
  const int wr = wv >> 2;     // 0..1 -> tile-rows 4*wr..4*wr+3
  const int wc = wv & 3;      // 0..3 -> tile-cols 2*wc..2*wc+1

  for (int it = 0; it < NITER; ++it) {
    const float kA = NS_C1[it];
    const float kB = NS_C2[it];
    const bool upd_y = (it != NITER - 1);   // last iter: Y' dead (traces use Z)

    // --- (a) W = Z*Y ---
    f32x4 acc[4][2];
#pragma unroll
    for (int r = 0; r < 4; ++r)
#pragma unroll
      for (int c2 = 0; c2 < 2; ++c2) acc[r][c2] = (f32x4)0.f;
#pragma unroll
    for (int ks = 0; ks < 4; ++ks) {
      s16x8 a[4], b[2];
#pragma unroll
      for (int r = 0; r < 4; ++r) a[r] = load_frag(Zb, (4 * wr + r) * 16, ks, lane);
#pragma unroll
      for (int c2 = 0; c2 < 2; ++c2) b[c2] = load_frag(Yb, (2 * wc + c2) * 16, ks, lane);
#pragma unroll
      for (int r = 0; r < 4; ++r)
#pragma unroll
        for (int c2 = 0; c2 < 2; ++c2)
          acc[r][c2] = __builtin_amdgcn_mfma_f32_16x16x32_bf16(a[r], b[c2], acc[r][c2], 0, 0, 0);
    }
    // --- (b) M = kA*I - kB*W, clamp, hi/lo split, transposed store ---
#pragma unroll
    for (int r = 0; r < 4; ++r) {
      int ibase = (4 * wr + r) * 16 + quad * 4;
      int cg    = ibase >> 3;
#pragma unroll
      for (int c2 = 0; c2 < 2; ++c2) {
        int jg  = (2 * wc + c2) * 16 + (lane & 15);
        int idx = jg * 128 + ((cg ^ (jg & 15)) << 3) + (ibase & 7);
        s16x4 vh, vl;
#pragma unroll
        for (int e = 0; e < 4; ++e) {
          float mv = -kB * acc[r][c2][e] + ((ibase + e == jg) ? kA : 0.f);
          mv = fminf(fmaxf(mv, -4.f), 4.f);
          unsigned short hh = f2bf(mv);
          vh[e] = (short)hh;
          vl[e] = (short)f2bf(mv - bf2f(hh));
        }
        *(s16x4*)(Mh + idx) = vh;
        *(s16x4*)(Ml + idx) = vl;
      }
    }
    __syncthreads();

    // --- (c) Y' = M*Y, Z' = M*Z (M = shared split-A; iterates commute) ---
    f32x4 ay[4][2], az[4][2];
#pragma unroll
    for (int r = 0; r < 4; ++r)
#pragma unroll
      for (int c2 = 0; c2 < 2; ++c2) { ay[r][c2] = (f32x4)0.f; az[r][c2] = (f32x4)0.f; }
#pragma unroll
    for (int ks = 0; ks < 4; ++ks) {
      s16x8 aMh[4], aMl[4], bY[2], bZ[2];
#pragma unroll
      for (int r = 0; r < 4; ++r) {
        int rb = (4 * wr + r) * 16;
        aMh[r] = load_frag(Mh, rb, ks, lane);
        aMl[r] = load_frag(Ml, rb, ks, lane);
      }
#pragma unroll
      for (int c2 = 0; c2 < 2; ++c2) {
        int cb = (2 * wc + c2) * 16;
        bY[c2] = load_frag(Yb, cb, ks, lane);
        bZ[c2] = load_frag(Zb, cb, ks, lane);
      }
#pragma unroll
      for (int r = 0; r < 4; ++r)
#pragma unroll
        for (int c2 = 0; c2 < 2; ++c2) {
          az[r][c2] = __builtin_amdgcn_mfma_f32_16x16x32_bf16(aMh[r], bZ[c2], az[r][c2], 0, 0, 0);
          az[r][c2] = __builtin_amdgcn_mfma_f32_16x16x32_bf16(aMl[r], bZ[c2], az[r][c2], 0, 0, 0);
          if (upd_y) {
            ay[r][c2] = __builtin_amdgcn_mfma_f32_16x16x32_bf16(aMh[r], bY[c2], ay[r][c2], 0, 0, 0);
            ay[r][c2] = __builtin_amdgcn_mfma_f32_16x16x32_bf16(aMl[r], bY[c2], ay[r][c2], 0, 0, 0);
          }
        }
    }
    __syncthreads();

    // --- (d) store Z' (and Y' unless last iter), transposed ---
#pragma unroll
    for (int r = 0; r < 4; ++r) {
      int ibase = (4 * wr + r) * 16 + quad * 4;
      int cg    = ibase >> 3;
#pragma unroll
      for (int c2 = 0; c2 < 2; ++c2) {
        int jg  = (2 * wc + c2) * 16 + (lane & 15);
        int idx = jg * 128 + ((cg ^ (jg & 15)) << 3) + (ibase & 7);
        s16x4 vy, vz;
#pragma unroll
        for (int e = 0; e < 4; ++e) {
          vy[e] = (short)f2bf(ay[r][c2][e]);
          vz[e] = (short)f2bf(az[r][c2][e]);
        }
        *(s16x4*)(Zb + idx) = vz;
        if (upd_y) *(s16x4*)(Yb + idx) = vy;
      }
    }
    __syncthreads();
  }

  // ---- traces: tr(GZ) (fp32 anchor in regs), tr(Z), tr(Z^3) ----
  float t_gz = 0.f, t_z = 0.f, t_z3 = 0.f;
  if (bid < NCLS) {
#pragma unroll
    for (int a = 0; a < 8; ++a) {
      s16x4 zv = *(const s16x4*)(Zb + swz_idx(i0 + a, j0));
#pragma unroll
      for (int b = 0; b < 4; ++b) t_gz += accg[a][b] * bf2f((unsigned short)zv[b]);
    }
  } else {
#pragma unroll
    for (int t = 0; t < 8; ++t) {
      int idx4 = tid + 512 * t;
      int flat = idx4 * 4, i = flat >> 7, jj = flat & 127;
      s16x4 zv = *(const s16x4*)(Zb + swz_idx(i, jj));
#pragma unroll
      for (int e = 0; e < 4; ++e) t_gz += ((const float*)&gs[t])[e] * bf2f((unsigned short)zv[e]);
    }
  }
  if (tid < DIM) t_z = bf2f((unsigned short)Zb[swz_idx(tid, tid)]);

  {  // U = Z*Z tile-wise; tr(Z^3) = sum U_ij * Z_ji
    f32x4 u[4][2];
#pragma unroll
    for (int r = 0; r < 4; ++r)
#pragma unroll
      for (int c2 = 0; c2 < 2; ++c2) u[r][c2] = (f32x4)0.f;
#pragma unroll
    for (int ks = 0; ks < 4; ++ks) {
      s16x8 a[4], b[2];
#pragma unroll
      for (int r = 0; r < 4; ++r) a[r] = load_frag(Zb, (4 * wr + r) * 16, ks, lane);
#pragma unroll
      for (int c2 = 0; c2 < 2; ++c2) b[c2] = load_frag(Zb, (2 * wc + c2) * 16, ks, lane);
#pragma unroll
      for (int r = 0; r < 4; ++r)
#pragma unroll
        for (int c2 = 0; c2 < 2; ++c2)
          u[r][c2] = __builtin_amdgcn_mfma_f32_16x16x32_bf16(a[r], b[c2], u[r][c2], 0, 0, 0);
    }
#pragma unroll
    for (int r = 0; r < 4; ++r) {
      int ibase = (4 * wr + r) * 16 + quad * 4;
      int cg    = ibase >> 3;
#pragma unroll
      for (int c2 = 0; c2 < 2; ++c2) {
        int jg  = (2 * wc + c2) * 16 + (lane & 15);
        int idx = jg * 128 + ((cg ^ (jg & 15)) << 3) + (ibase & 7);
        s16x4 zt = *(const s16x4*)(Zb + idx);
#pragma unroll
        for (int e = 0; e < 4; ++e) t_z3 += u[r][c2][e] * bf2f((unsigned short)zt[e]);
      }
    }
  }

  for (int off = 32; off > 0; off >>= 1) {
    t_gz += __shfl_down(t_gz, off, 64);
    t_z  += __shfl_down(t_z,  off, 64);
    t_z3 += __shfl_down(t_z3, off, 64);
  }
  __syncthreads();
  float* red = (float*)Mh;             // Mh dead after last iter
  if (lane == 0) { red[wv] = t_gz; red[8 + wv] = t_z; red[16 + wv] = t_z3; }
  __syncthreads();

  float nuc_own = 0.f;
  if (tid == 0) {
    float gz = 0.f, z1 = 0.f, z3 = 0.f;
#pragma unroll
    for (int w = 0; w < 8; ++w) { gz += red[w]; z1 += red[8 + w]; z3 += red[16 + w]; }
    float trsq = gz * invs + 0.5f * eps * z1 - 0.125f * eps * eps * z3;
    nuc_own = sqrtf(s) * trsq;
    nuc[bid] = nuc_own;
  }

  if (bid < NCLS) {
    if (tid == 0) flag_set(&nflag[bid]);
    return;
  }

  // ======== block 64: final combine (parallel poll, one flag/lane) ========
  if (tid < NCLS)          flag_wait(&nflag[tid]);
  else if (tid < 2 * NCLS) flag_wait(&ceflag[tid - NCLS]);
  __syncthreads();

  float ce2 = cepart[tid];                       // 512 entries, 512 threads
  float vmx = (tid < NCLS) ? fmaxf(nuc[tid], DELTA_) : 0.f;
  for (int off = 32; off > 0; off >>= 1) {
    vmx += __shfl_down(vmx, off, 64);
    ce2 += __shfl_down(ce2, off, 64);
  }
  if (lane == 0) { red[wv] = vmx; red[8 + wv] = ce2; }
  __syncthreads();
  if (tid == 0) {
    float vs = 0.f, cs = 0.f;
#pragma unroll
    for (int w = 0; w < 8; ++w) { vs += red[w]; cs += red[8 + w]; }
    float ole = (vs - nuc_own) * (LAMBDA_ / (float)N_ROWS);
    out[0] = ole + cs / (float)N_ROWS;
  }
}

extern "C" void kernel_launch(void* const* d_in, const int* in_sizes, int n_in,
                              void* d_out, int out_size, void* d_ws, size_t ws_size,
                              hipStream_t stream) {
  const float* logits = (const float*)d_in[0];   // out  [8192,64]
  const float* feat   = (const float*)d_in[1];   // feat [8192,128]
  const int*   yp     = (const int*)d_in[2];     // y    [8192]

  int*   flags  = (int*)d_ws;                    // 256 ints (208 used)
  float* nuc    = (float*)d_ws + 256;            // 68
  float* cepart = nuc + 68;                      // 512
  float* G      = cepart + 512;                  // 65 x 16384 (Gall = idx 64)

  // Zero the flag region (workspace is poisoned each run; keeps flag
  // semantics independent of harness re-poison timing). Graph-capture-safe.
  hipMemsetAsync(d_ws, 0, 256 * sizeof(int), stream);

  ole_fused<<<NCLS + 1 + NB_CE + NB_BLD, 512, 0, stream>>>(
      feat, yp, logits, G, nuc, cepart, flags, (float*)d_out);
}

// Round 7
// 127.604 us; speedup vs baseline: 1.0985x; 1.0077x over previous
//
#include <hip/hip_runtime.h>
#include <math.h>

// OLE loss on MI355X — FUSED single kernel, R22.
// ||X_c||* = trace(sqrt(G_c)), G_c = X_c^T X_c (128x128).
// R22 = R21 (NITER=6, last-iter Y-skip) with the final iteration PEELED
// instead of guarded: R21's runtime `if (upd_y)` sat inside the unrolled
// MFMA cluster (~32 branch instances) and regressed the NS loop 78.8->87.9us
// (MfmaUtil 4.6->3.3%, -28% — more than the 15% work removal; the branch
// broke R18's clean ay/az interleave). Main loop (it=0..4) is R18's
// branch-free body byte-for-byte; the peeled final step computes only
// Z' = M*Z (no ay accs, no bY loads, no Y store, zero branches).
// Evidence trail: bank-conflict counter scaled 482820->399620 exactly with
// 7->6 iters — NS-internal, ~1us, not worth chasing (R17/R21).
// Kept: builders tree-sum Gall (R16; atomics = 16.4MB RMW drain), ballot
// list, flag dataflow, 512t/8-wave/4x2-frag engine (R15/R18; 1024t pins
// VGPR=64 — R16/R17; reg-caching spills at >128 live — R20).
// Lessons: R4 (M hi/lo split), R8 (grid.sync ~50us), R11 (one flag/lane),
// R14+R21 (NITER=6 sufficient: |w-1|<=1e-5 by k6, loss err ~6e-6).

#define N_ROWS 8192
#define DIM    128
#define NCLS   64
#define NB_CE  64
#define NB_BLD 16
#define NITER  6
#define EPSN   2e-4f
#define LAMBDA_ 0.25f
#define DELTA_  1.0f
#define MAGIC  0x13579BDF   // != 0xAAAAAAAA poison, != 0

typedef __attribute__((ext_vector_type(8))) short s16x8;  // 8 bf16 = 4 VGPR
typedef __attribute__((ext_vector_type(4))) short s16x4;  // 4 bf16
typedef __attribute__((ext_vector_type(4))) float f32x4;

// Scaled-NS ladder: M_k = C1[k]*I - C2[k]*W, C1 = 1.5*sqrt(t), C2 = 0.5*t^1.5.
// t-schedule {2.9, 2.758, 2.13, 1.868, 1.264, 1}; |w-1|<=1e-5 after step 6.
static __device__ const float NS_C1[NITER] =
  {2.554408f, 2.491084f, 2.189178f, 2.050122f, 1.686417f, 1.5f};
static __device__ const float NS_C2[NITER] =
  {2.469261f, 2.290137f, 1.554316f, 1.276543f, 0.710544f, 0.5f};

__device__ __forceinline__ unsigned short f2bf(float f) {   // RNE
  unsigned u = __float_as_uint(f);
  u = (u + 0x7FFFu + ((u >> 16) & 1u)) >> 16;
  return (unsigned short)u;
}
__device__ __forceinline__ float bf2f(unsigned short h) {
  return __uint_as_float(((unsigned)h) << 16);
}

// bf16 LDS: element (i,j) at short-index i*128 + (((j>>3)^(i&15))<<3) + (j&7)
__device__ __forceinline__ int swz_idx(int i, int j) {
  return i * 128 + (((j >> 3) ^ (i & 15)) << 3) + (j & 7);
}

__device__ __forceinline__ s16x8 load_frag(const short* buf, int row0,
                                           int kstep, int lane) {
  int m  = row0 + (lane & 15);
  int kg = kstep * 4 + (lane >> 4);
  return *(const s16x8*)(buf + m * 128 + ((kg ^ (m & 15)) << 3));
}

__device__ __forceinline__ void flag_set(int* p) {
  __threadfence();
  __hip_atomic_store(p, MAGIC, __ATOMIC_RELEASE, __HIP_MEMORY_SCOPE_AGENT);
}
__device__ __forceinline__ void flag_wait(const int* p) {
  while (__hip_atomic_load(p, __ATOMIC_ACQUIRE, __HIP_MEMORY_SCOPE_AGENT) != MAGIC)
    __builtin_amdgcn_s_sleep(8);
}

// ---------------------------------------------------------------------------
// Fused kernel: 145 blocks x 512 threads (8 waves, 2/SIMD, VGPR 128).
//  0..63   : ballot list -> LDS-staged Gram -> store G_c -> gramdone
//            -> NS(G_c, reg anchor) -> nuc[c] -> nflag
//  64      : wait gallf[16] -> load Gall -> NS -> wait nflag/ceflag -> out
//  65..128 : CE (512 waves total) -> cepart -> ceflag
//  129..144: wait gramdone[64] -> tree-sum G_c slice -> Gall -> gallf
// ---------------------------------------------------------------------------
__global__ __launch_bounds__(512, 1) void ole_fused(const float* __restrict__ feat,
                                                    const int* __restrict__ y,
                                                    const float* __restrict__ logits,
                                                    float* __restrict__ G,
                                                    float* __restrict__ nuc,
                                                    float* __restrict__ cepart,
                                                    int* __restrict__ flags,
                                                    float* __restrict__ out) {
  int* gramdone = flags;            // 64
  int* gallf    = flags + 64;       // 16
  int* nflag    = flags + 80;       // 64
  int* ceflag   = flags + 144;      // 64

  __shared__ __align__(16) short Yb[DIM * DIM];
  __shared__ __align__(16) short Mh[DIM * DIM];
  __shared__ __align__(16) short Ml[DIM * DIM];
  __shared__ __align__(16) short Zb[DIM * DIM];
  __shared__ int cnt;

  const int bid  = blockIdx.x;
  const int tid  = threadIdx.x;
  const int lane = tid & 63;
  const int quad = lane >> 4;
  const int wv   = tid >> 6;    // 0..7

  float* Gall = G + (size_t)NCLS * DIM * DIM;

  // ---------------- CE blocks (65..128): 512 waves total ----------------
  if (bid > NCLS && bid <= NCLS + NB_CE) {
    const int gwave = (bid - NCLS - 1) * 8 + wv;
    float acc = 0.f;
    for (int row = gwave; row < N_ROWS; row += 512) {
      float v = logits[row * NCLS + lane];
      float mx = v;
      for (int off = 32; off > 0; off >>= 1) mx = fmaxf(mx, __shfl_xor(mx, off, 64));
      float e = expf(v - mx);
      for (int off = 32; off > 0; off >>= 1) e += __shfl_xor(e, off, 64);
      if (lane == 0) {
        int t = y[row];
        acc += (mx + logf(e)) - logits[row * NCLS + t];
      }
    }
    if (lane == 0) cepart[gwave] = acc;
    __syncthreads();
    if (tid == 0) flag_set(&ceflag[bid - NCLS - 1]);
    return;
  }

  // ---------------- builder blocks (129..144) ----------------
  if (bid > NCLS + NB_CE) {
    const int gb = bid - (NCLS + 1 + NB_CE);        // 0..15
    if (tid < NCLS) flag_wait(&gramdone[tid]);      // one flag per lane
    __syncthreads();
    if (tid < 256) {
      const int idx4 = gb * 256 + tid;              // 16 x 256 = 4096 float4s
      const float4* G4 = (const float4*)G;
      float4 s = make_float4(0.f, 0.f, 0.f, 0.f);
#pragma unroll 8
      for (int c = 0; c < NCLS; ++c) {
        float4 v = G4[(size_t)c * (DIM * DIM / 4) + idx4];
        s.x += v.x; s.y += v.y; s.z += v.z; s.w += v.w;
      }
      ((float4*)Gall)[idx4] = s;
    }
    __syncthreads();
    if (tid == 0) flag_set(&gallf[gb]);
    return;
  }

  // ====================== gram + NS blocks (0..64) ======================
  // 512 threads = 16x32 grid; thread owns 8x4 patch (i0..i0+7, j0..j0+3)
  const int ti = tid >> 5, tj = tid & 31;
  const int i0 = ti * 8,  j0 = tj * 4;

  float tpart = 0.f, fpart = 0.f;
  float4 gs[8];        // block 64 only: Gall slice (NS anchor)
  float  accg[8][4];   // class only: fp32 G_c patch (NS anchor)

  if (bid < NCLS) {
    // ---- ballot-compacted row list (one lane-0 atomicAdd per 64 rows) ----
    int* list = (int*)Yb;                       // up to 8192 ints (= Yb)
    if (tid == 0) cnt = 0;
    __syncthreads();
#pragma unroll
    for (int t = 0; t < 16; ++t) {
      int row = t * 512 + tid;
      bool hit = (y[row] == bid);
      unsigned long long m = __ballot(hit);
      int base = 0;
      if (lane == 0 && m) base = atomicAdd(&cnt, __popcll(m));
      base = __shfl(base, 0, 64);
      if (hit) {
        int pre = __popcll(m & ((1ull << lane) - 1ull));
        list[base + pre] = row;
      }
    }
    __syncthreads();
    const int n = cnt;

    float (*xs)[DIM] = (float (*)[DIM])Mh;      // 16x128 f32 = 8 KB (in Mh)

#pragma unroll
    for (int a = 0; a < 8; ++a)
#pragma unroll
      for (int b = 0; b < 4; ++b) accg[a][b] = 0.f;

    for (int base = 0; base < n; base += 16) {
      int li = base + ti;                       // ti doubles as load-row
      float4 v = make_float4(0.f, 0.f, 0.f, 0.f);
      if (li < n) v = *(const float4*)(feat + (size_t)list[li] * DIM + j0);
      __syncthreads();                          // prev chunk's reads done
      *(float4*)(&xs[ti][j0]) = v;
      __syncthreads();
#pragma unroll
      for (int rw = 0; rw < 16; ++rw) {
        float xi[8], xj[4];
#pragma unroll
        for (int a = 0; a < 8; ++a) xi[a] = xs[rw][i0 + a];
#pragma unroll
        for (int b = 0; b < 4; ++b) xj[b] = xs[rw][j0 + b];
#pragma unroll
        for (int a = 0; a < 8; ++a)
#pragma unroll
          for (int b = 0; b < 4; ++b) accg[a][b] = fmaf(xi[a], xj[b], accg[a][b]);
      }
    }

    // stats + store G_c (plain stores; flag pattern proven by cepart/nuc)
    float* Gc = G + (size_t)bid * DIM * DIM;
#pragma unroll
    for (int a = 0; a < 8; ++a) {
      float4 row;
      float* rp = (float*)&row;
#pragma unroll
      for (int b = 0; b < 4; ++b) {
        float g = accg[a][b];
        rp[b] = g;
        fpart += g * g;
        if (i0 + a == j0 + b) tpart += g;
      }
      *(float4*)(Gc + (size_t)(i0 + a) * DIM + j0) = row;
    }
    __syncthreads();   // all threads' stores drained (vmcnt0 at barrier)
    if (tid == 0) flag_set(&gramdone[bid]);
    // list (Yb) / xs (Mh) dead from here.
  } else {
    // ---- block 64: wait for builders, load Gall ----
    if (tid < NB_BLD) flag_wait(&gallf[tid]);   // one flag per lane
    __syncthreads();
    const float4* Gm4 = (const float4*)Gall;
#pragma unroll
    for (int t = 0; t < 8; ++t) {
      int idx4 = tid + 512 * t;
      float4 v = Gm4[idx4];
      gs[t] = v;
      fpart += v.x * v.x + v.y * v.y + v.z * v.z + v.w * v.w;
      int flat = idx4 * 4, i = flat >> 7, jj = flat & 127;
      if (jj <= i && i < jj + 4) tpart += ((const float*)&v)[i - jj];
    }
  }

  // ---- reduce trace / fro2 across 8 waves ----
  for (int off = 32; off > 0; off >>= 1) {
    tpart += __shfl_down(tpart, off, 64);
    fpart += __shfl_down(fpart, off, 64);
  }
  float* redf = (float*)Zb;           // Zb not yet initialized
  if (lane == 0) { redf[wv] = tpart; redf[8 + wv] = fpart; }
  __syncthreads();
  float trace = 0.f, fro2 = 0.f;
#pragma unroll
  for (int w = 0; w < 8; ++w) { trace += redf[w]; fro2 += redf[8 + w]; }
  __syncthreads();                    // redf reads done -> Zb reusable

  float s = sqrtf(fro2);
  if (s < 1e-12f) s = 1.f;
  const float invs = 1.f / s;
  const float eps  = EPSN * trace * invs;

  // ---- init: Y0 = G/s + eps*I (single bf16), Z0 = I ----
  if (bid < NCLS) {
#pragma unroll
    for (int a = 0; a < 8; ++a) {
      int i = i0 + a;
      s16x4 vh;
#pragma unroll
      for (int b = 0; b < 4; ++b) {
        float x = accg[a][b] * invs + ((i == j0 + b) ? eps : 0.f);
        vh[b] = (short)f2bf(x);
      }
      *(s16x4*)(Yb + swz_idx(i, j0)) = vh;
    }
  } else {
#pragma unroll
    for (int t = 0; t < 8; ++t) {
      int idx4 = tid + 512 * t;
      int flat = idx4 * 4, i = flat >> 7, jj = flat & 127;
      s16x4 vh;
#pragma unroll
      for (int e = 0; e < 4; ++e) {
        float x = ((const float*)&gs[t])[e] * invs + ((i == jj + e) ? eps : 0.f);
        vh[e] = (short)f2bf(x);
      }
      *(s16x4*)(Yb + swz_idx(i, jj)) = vh;
    }
  }
  for (int grp = tid; grp < DIM * 16; grp += 512) {
    int i = grp >> 4, g = grp & 15;
    s16x8 v = (s16x8)0;
    if ((i >> 3) == g) v[i & 7] = (short)0x3F80;   // 1.0 bf16
    *(s16x8*)(Zb + i * 128 + ((g ^ (i & 15)) << 3)) = v;
  }
  __syncthreads();

  // 8 waves: 2x4 wave grid, each wave owns a 64x32 output tile (4x2 frags)
  const int wr = wv >> 2;     // 0..1 -> tile-rows 4*wr..4*wr+3
  const int wc = wv & 3;      // 0..3 -> tile-cols 2*wc..2*wc+1

  // ======== main loop: it = 0..NITER-2, branch-free R18 body ========
  for (int it = 0; it < NITER - 1; ++it) {
    const float kA = NS_C1[it];
    const float kB = NS_C2[it];

    // --- (a) W = Z*Y ---
    f32x4 acc[4][2];
#pragma unroll
    for (int r = 0; r < 4; ++r)
#pragma unroll
      for (int c2 = 0; c2 < 2; ++c2) acc[r][c2] = (f32x4)0.f;
#pragma unroll
    for (int ks = 0; ks < 4; ++ks) {
      s16x8 a[4], b[2];
#pragma unroll
      for (int r = 0; r < 4; ++r) a[r] = load_frag(Zb, (4 * wr + r) * 16, ks, lane);
#pragma unroll
      for (int c2 = 0; c2 < 2; ++c2) b[c2] = load_frag(Yb, (2 * wc + c2) * 16, ks, lane);
#pragma unroll
      for (int r = 0; r < 4; ++r)
#pragma unroll
        for (int c2 = 0; c2 < 2; ++c2)
          acc[r][c2] = __builtin_amdgcn_mfma_f32_16x16x32_bf16(a[r], b[c2], acc[r][c2], 0, 0, 0);
    }
    // --- (b) M = kA*I - kB*W, clamp, hi/lo split, transposed store ---
#pragma unroll
    for (int r = 0; r < 4; ++r) {
      int ibase = (4 * wr + r) * 16 + quad * 4;
      int cg    = ibase >> 3;
#pragma unroll
      for (int c2 = 0; c2 < 2; ++c2) {
        int jg  = (2 * wc + c2) * 16 + (lane & 15);
        int idx = jg * 128 + ((cg ^ (jg & 15)) << 3) + (ibase & 7);
        s16x4 vh, vl;
#pragma unroll
        for (int e = 0; e < 4; ++e) {
          float mv = -kB * acc[r][c2][e] + ((ibase + e == jg) ? kA : 0.f);
          mv = fminf(fmaxf(mv, -4.f), 4.f);
          unsigned short hh = f2bf(mv);
          vh[e] = (short)hh;
          vl[e] = (short)f2bf(mv - bf2f(hh));
        }
        *(s16x4*)(Mh + idx) = vh;
        *(s16x4*)(Ml + idx) = vl;
      }
    }
    __syncthreads();

    // --- (c) Y' = M*Y, Z' = M*Z (M = shared split-A; iterates commute) ---
    f32x4 ay[4][2], az[4][2];
#pragma unroll
    for (int r = 0; r < 4; ++r)
#pragma unroll
      for (int c2 = 0; c2 < 2; ++c2) { ay[r][c2] = (f32x4)0.f; az[r][c2] = (f32x4)0.f; }
#pragma unroll
    for (int ks = 0; ks < 4; ++ks) {
      s16x8 aMh[4], aMl[4], bY[2], bZ[2];
#pragma unroll
      for (int r = 0; r < 4; ++r) {
        int rb = (4 * wr + r) * 16;
        aMh[r] = load_frag(Mh, rb, ks, lane);
        aMl[r] = load_frag(Ml, rb, ks, lane);
      }
#pragma unroll
      for (int c2 = 0; c2 < 2; ++c2) {
        int cb = (2 * wc + c2) * 16;
        bY[c2] = load_frag(Yb, cb, ks, lane);
        bZ[c2] = load_frag(Zb, cb, ks, lane);
      }
#pragma unroll
      for (int r = 0; r < 4; ++r)
#pragma unroll
        for (int c2 = 0; c2 < 2; ++c2) {
          ay[r][c2] = __builtin_amdgcn_mfma_f32_16x16x32_bf16(aMh[r], bY[c2], ay[r][c2], 0, 0, 0);
          ay[r][c2] = __builtin_amdgcn_mfma_f32_16x16x32_bf16(aMl[r], bY[c2], ay[r][c2], 0, 0, 0);
          az[r][c2] = __builtin_amdgcn_mfma_f32_16x16x32_bf16(aMh[r], bZ[c2], az[r][c2], 0, 0, 0);
          az[r][c2] = __builtin_amdgcn_mfma_f32_16x16x32_bf16(aMl[r], bZ[c2], az[r][c2], 0, 0, 0);
        }
    }
    __syncthreads();

    // --- (d) store Y' (single), Z' (single), transposed ---
#pragma unroll
    for (int r = 0; r < 4; ++r) {
      int ibase = (4 * wr + r) * 16 + quad * 4;
      int cg    = ibase >> 3;
#pragma unroll
      for (int c2 = 0; c2 < 2; ++c2) {
        int jg  = (2 * wc + c2) * 16 + (lane & 15);
        int idx = jg * 128 + ((cg ^ (jg & 15)) << 3) + (ibase & 7);
        s16x4 vy, vz;
#pragma unroll
        for (int e = 0; e < 4; ++e) {
          vy[e] = (short)f2bf(ay[r][c2][e]);
          vz[e] = (short)f2bf(az[r][c2][e]);
        }
        *(s16x4*)(Yb + idx) = vy;
        *(s16x4*)(Zb + idx) = vz;
      }
    }
    __syncthreads();
  }

  // ======== peeled final iteration: Z' = M*Z only (Y dead) ========
  {
    const float kA = NS_C1[NITER - 1];
    const float kB = NS_C2[NITER - 1];

    // --- (a) W = Z*Y ---
    f32x4 acc[4][2];
#pragma unroll
    for (int r = 0; r < 4; ++r)
#pragma unroll
      for (int c2 = 0; c2 < 2; ++c2) acc[r][c2] = (f32x4)0.f;
#pragma unroll
    for (int ks = 0; ks < 4; ++ks) {
      s16x8 a[4], b[2];
#pragma unroll
      for (int r = 0; r < 4; ++r) a[r] = load_frag(Zb, (4 * wr + r) * 16, ks, lane);
#pragma unroll
      for (int c2 = 0; c2 < 2; ++c2) b[c2] = load_frag(Yb, (2 * wc + c2) * 16, ks, lane);
#pragma unroll
      for (int r = 0; r < 4; ++r)
#pragma unroll
        for (int c2 = 0; c2 < 2; ++c2)
          acc[r][c2] = __builtin_amdgcn_mfma_f32_16x16x32_bf16(a[r], b[c2], acc[r][c2], 0, 0, 0);
    }
    // --- (b) M = kA*I - kB*W ---
#pragma unroll
    for (int r = 0; r < 4; ++r) {
      int ibase = (4 * wr + r) * 16 + quad * 4;
      int cg    = ibase >> 3;
#pragma unroll
      for (int c2 = 0; c2 < 2; ++c2) {
        int jg  = (2 * wc + c2) * 16 + (lane & 15);
        int idx = jg * 128 + ((cg ^ (jg & 15)) << 3) + (ibase & 7);
        s16x4 vh, vl;
#pragma unroll
        for (int e = 0; e < 4; ++e) {
          float mv = -kB * acc[r][c2][e] + ((ibase + e == jg) ? kA : 0.f);
          mv = fminf(fmaxf(mv, -4.f), 4.f);
          unsigned short hh = f2bf(mv);
          vh[e] = (short)hh;
          vl[e] = (short)f2bf(mv - bf2f(hh));
        }
        *(s16x4*)(Mh + idx) = vh;
        *(s16x4*)(Ml + idx) = vl;
      }
    }
    __syncthreads();

    // --- (c) Z' = M*Z only ---
    f32x4 az[4][2];
#pragma unroll
    for (int r = 0; r < 4; ++r)
#pragma unroll
      for (int c2 = 0; c2 < 2; ++c2) az[r][c2] = (f32x4)0.f;
#pragma unroll
    for (int ks = 0; ks < 4; ++ks) {
      s16x8 aMh[4], aMl[4], bZ[2];
#pragma unroll
      for (int r = 0; r < 4; ++r) {
        int rb = (4 * wr + r) * 16;
        aMh[r] = load_frag(Mh, rb, ks, lane);
        aMl[r] = load_frag(Ml, rb, ks, lane);
      }
#pragma unroll
      for (int c2 = 0; c2 < 2; ++c2)
        bZ[c2] = load_frag(Zb, (2 * wc + c2) * 16, ks, lane);
#pragma unroll
      for (int r = 0; r < 4; ++r)
#pragma unroll
        for (int c2 = 0; c2 < 2; ++c2) {
          az[r][c2] = __builtin_amdgcn_mfma_f32_16x16x32_bf16(aMh[r], bZ[c2], az[r][c2], 0, 0, 0);
          az[r][c2] = __builtin_amdgcn_mfma_f32_16x16x32_bf16(aMl[r], bZ[c2], az[r][c2], 0, 0, 0);
        }
    }
    __syncthreads();

    // --- (d) store Z' only ---
#pragma unroll
    for (int r = 0; r < 4; ++r) {
      int ibase = (4 * wr + r) * 16 + quad * 4;
      int cg    = ibase >> 3;
#pragma unroll
      for (int c2 = 0; c2 < 2; ++c2) {
        int jg  = (2 * wc + c2) * 16 + (lane & 15);
        int idx = jg * 128 + ((cg ^ (jg & 15)) << 3) + (ibase & 7);
        s16x4 vz;
#pragma unroll
        for (int e = 0; e < 4; ++e) vz[e] = (short)f2bf(az[r][c2][e]);
        *(s16x4*)(Zb + idx) = vz;
      }
    }
    __syncthreads();
  }

  // ---- traces: tr(GZ) (fp32 anchor in regs), tr(Z), tr(Z^3) ----
  float t_gz = 0.f, t_z = 0.f, t_z3 = 0.f;
  if (bid < NCLS) {
#pragma unroll
    for (int a = 0; a < 8; ++a) {
      s16x4 zv = *(const s16x4*)(Zb + swz_idx(i0 + a, j0));
#pragma unroll
      for (int b = 0; b < 4; ++b) t_gz += accg[a][b] * bf2f((unsigned short)zv[b]);
    }
  } else {
#pragma unroll
    for (int t = 0; t < 8; ++t) {
      int idx4 = tid + 512 * t;
      int flat = idx4 * 4, i = flat >> 7, jj = flat & 127;
      s16x4 zv = *(const s16x4*)(Zb + swz_idx(i, jj));
#pragma unroll
      for (int e = 0; e < 4; ++e) t_gz += ((const float*)&gs[t])[e] * bf2f((unsigned short)zv[e]);
    }
  }
  if (tid < DIM) t_z = bf2f((unsigned short)Zb[swz_idx(tid, tid)]);

  {  // U = Z*Z tile-wise; tr(Z^3) = sum U_ij * Z_ji
    f32x4 u[4][2];
#pragma unroll
    for (int r = 0; r < 4; ++r)
#pragma unroll
      for (int c2 = 0; c2 < 2; ++c2) u[r][c2] = (f32x4)0.f;
#pragma unroll
    for (int ks = 0; ks < 4; ++ks) {
      s16x8 a[4], b[2];
#pragma unroll
      for (int r = 0; r < 4; ++r) a[r] = load_frag(Zb, (4 * wr + r) * 16, ks, lane);
#pragma unroll
      for (int c2 = 0; c2 < 2; ++c2) b[c2] = load_frag(Zb, (2 * wc + c2) * 16, ks, lane);
#pragma unroll
      for (int r = 0; r < 4; ++r)
#pragma unroll
        for (int c2 = 0; c2 < 2; ++c2)
          u[r][c2] = __builtin_amdgcn_mfma_f32_16x16x32_bf16(a[r], b[c2], u[r][c2], 0, 0, 0);
    }
#pragma unroll
    for (int r = 0; r < 4; ++r) {
      int ibase = (4 * wr + r) * 16 + quad * 4;
      int cg    = ibase >> 3;
#pragma unroll
      for (int c2 = 0; c2 < 2; ++c2) {
        int jg  = (2 * wc + c2) * 16 + (lane & 15);
        int idx = jg * 128 + ((cg ^ (jg & 15)) << 3) + (ibase & 7);
        s16x4 zt = *(const s16x4*)(Zb + idx);
#pragma unroll
        for (int e = 0; e < 4; ++e) t_z3 += u[r][c2][e] * bf2f((unsigned short)zt[e]);
      }
    }
  }

  for (int off = 32; off > 0; off >>= 1) {
    t_gz += __shfl_down(t_gz, off, 64);
    t_z  += __shfl_down(t_z,  off, 64);
    t_z3 += __shfl_down(t_z3, off, 64);
  }
  __syncthreads();
  float* red = (float*)Mh;             // Mh dead after last iter
  if (lane == 0) { red[wv] = t_gz; red[8 + wv] = t_z; red[16 + wv] = t_z3; }
  __syncthreads();

  float nuc_own = 0.f;
  if (tid == 0) {
    float gz = 0.f, z1 = 0.f, z3 = 0.f;
#pragma unroll
    for (int w = 0; w < 8; ++w) { gz += red[w]; z1 += red[8 + w]; z3 += red[16 + w]; }
    float trsq = gz * invs + 0.5f * eps * z1 - 0.125f * eps * eps * z3;
    nuc_own = sqrtf(s) * trsq;
    nuc[bid] = nuc_own;
  }

  if (bid < NCLS) {
    if (tid == 0) flag_set(&nflag[bid]);
    return;
  }

  // ======== block 64: final combine (parallel poll, one flag/lane) ========
  if (tid < NCLS)          flag_wait(&nflag[tid]);
  else if (tid < 2 * NCLS) flag_wait(&ceflag[tid - NCLS]);
  __syncthreads();

  float ce2 = cepart[tid];                       // 512 entries, 512 threads
  float vmx = (tid < NCLS) ? fmaxf(nuc[tid], DELTA_) : 0.f;
  for (int off = 32; off > 0; off >>= 1) {
    vmx += __shfl_down(vmx, off, 64);
    ce2 += __shfl_down(ce2, off, 64);
  }
  if (lane == 0) { red[wv] = vmx; red[8 + wv] = ce2; }
  __syncthreads();
  if (tid == 0) {
    float vs = 0.f, cs = 0.f;
#pragma unroll
    for (int w = 0; w < 8; ++w) { vs += red[w]; cs += red[8 + w]; }
    float ole = (vs - nuc_own) * (LAMBDA_ / (float)N_ROWS);
    out[0] = ole + cs / (float)N_ROWS;
  }
}

extern "C" void kernel_launch(void* const* d_in, const int* in_sizes, int n_in,
                              void* d_out, int out_size, void* d_ws, size_t ws_size,
                              hipStream_t stream) {
  const float* logits = (const float*)d_in[0];   // out  [8192,64]
  const float* feat   = (const float*)d_in[1];   // feat [8192,128]
  const int*   yp     = (const int*)d_in[2];     // y    [8192]

  int*   flags  = (int*)d_ws;                    // 256 ints (208 used)
  float* nuc    = (float*)d_ws + 256;            // 68
  float* cepart = nuc + 68;                      // 512
  float* G      = cepart + 512;                  // 65 x 16384 (Gall = idx 64)

  // Zero the flag region (workspace is poisoned each run; keeps flag
  // semantics independent of harness re-poison timing). Graph-capture-safe.
  hipMemsetAsync(d_ws, 0, 256 * sizeof(int), stream);

  ole_fused<<<NCLS + 1 + NB_CE + NB_BLD, 512, 0, stream>>>(
      feat, yp, logits, G, nuc, cepart, flags, (float*)d_out);
}

// Round 8
// 125.450 us; speedup vs baseline: 1.1174x; 1.0172x over previous
//
#include <hip/hip_runtime.h>
#include <math.h>

// OLE loss on MI355X — FUSED single kernel, R23.
// ||X_c||* = trace(sqrt(G_c)), G_c = X_c^T X_c (128x128).
// R23 = R22 (best: 73.4us dispatch / 127.6 bench) + PIPELINED GRAM STAGING:
// Occupancy counter (6.5%) back-computation showed class blocks live ~55us
// -> gram phase is ~10-12us, not ~6: 8 serial chunks x (2 barriers + cold
// scattered 16-row feat load with latency fully exposed). Fix: ping-pong
// xs[2][16][128] (16KB, still aliased in Mh): issue chunk k+1 loads BEFORE
// computing chunk k, write to the other buffer, ONE barrier per chunk.
// Load latency hides under the 512-FMA compute. Gram ~4-5us; every NS
// chain (classes AND block64 via builders) starts earlier.
// NS engine unchanged from R22: 5 full branch-free R18 iterations + peeled
// final Z-only step (R21's runtime `if(upd_y)` in the MFMA cluster cost
// 14us of scheduling — peel, don't guard).
// Kept: builders tree-sum Gall (R16), ballot list, flag dataflow,
// 512t/8-wave/4x2-frag engine (1024t pins VGPR=64 — R16/R17; reg-caching
// >128 live spills to scratch, WRITE_SIZE 4->11MB — R20).
// Lessons: R4 (M hi/lo split), R8 (grid.sync ~50us), R11 (one flag/lane),
// R14+R21 (NITER=6: |w-1|<=1e-5 by k6), R17/R21 (bank conflicts NS-internal,
// scale with NITER, ~1us).

#define N_ROWS 8192
#define DIM    128
#define NCLS   64
#define NB_CE  64
#define NB_BLD 16
#define NITER  6
#define EPSN   2e-4f
#define LAMBDA_ 0.25f
#define DELTA_  1.0f
#define MAGIC  0x13579BDF   // != 0xAAAAAAAA poison, != 0

typedef __attribute__((ext_vector_type(8))) short s16x8;  // 8 bf16 = 4 VGPR
typedef __attribute__((ext_vector_type(4))) short s16x4;  // 4 bf16
typedef __attribute__((ext_vector_type(4))) float f32x4;

// Scaled-NS ladder: M_k = C1[k]*I - C2[k]*W, C1 = 1.5*sqrt(t), C2 = 0.5*t^1.5.
// t-schedule {2.9, 2.758, 2.13, 1.868, 1.264, 1}; |w-1|<=1e-5 after step 6.
static __device__ const float NS_C1[NITER] =
  {2.554408f, 2.491084f, 2.189178f, 2.050122f, 1.686417f, 1.5f};
static __device__ const float NS_C2[NITER] =
  {2.469261f, 2.290137f, 1.554316f, 1.276543f, 0.710544f, 0.5f};

__device__ __forceinline__ unsigned short f2bf(float f) {   // RNE
  unsigned u = __float_as_uint(f);
  u = (u + 0x7FFFu + ((u >> 16) & 1u)) >> 16;
  return (unsigned short)u;
}
__device__ __forceinline__ float bf2f(unsigned short h) {
  return __uint_as_float(((unsigned)h) << 16);
}

// bf16 LDS: element (i,j) at short-index i*128 + (((j>>3)^(i&15))<<3) + (j&7)
__device__ __forceinline__ int swz_idx(int i, int j) {
  return i * 128 + (((j >> 3) ^ (i & 15)) << 3) + (j & 7);
}

__device__ __forceinline__ s16x8 load_frag(const short* buf, int row0,
                                           int kstep, int lane) {
  int m  = row0 + (lane & 15);
  int kg = kstep * 4 + (lane >> 4);
  return *(const s16x8*)(buf + m * 128 + ((kg ^ (m & 15)) << 3));
}

__device__ __forceinline__ void flag_set(int* p) {
  __threadfence();
  __hip_atomic_store(p, MAGIC, __ATOMIC_RELEASE, __HIP_MEMORY_SCOPE_AGENT);
}
__device__ __forceinline__ void flag_wait(const int* p) {
  while (__hip_atomic_load(p, __ATOMIC_ACQUIRE, __HIP_MEMORY_SCOPE_AGENT) != MAGIC)
    __builtin_amdgcn_s_sleep(8);
}

// ---------------------------------------------------------------------------
// Fused kernel: 145 blocks x 512 threads (8 waves, 2/SIMD, VGPR 128).
//  0..63   : ballot list -> pipelined LDS-staged Gram -> store G_c ->
//            gramdone -> NS(G_c, reg anchor) -> nuc[c] -> nflag
//  64      : wait gallf[16] -> load Gall -> NS -> wait nflag/ceflag -> out
//  65..128 : CE (512 waves total) -> cepart -> ceflag
//  129..144: wait gramdone[64] -> tree-sum G_c slice -> Gall -> gallf
// ---------------------------------------------------------------------------
__global__ __launch_bounds__(512, 1) void ole_fused(const float* __restrict__ feat,
                                                    const int* __restrict__ y,
                                                    const float* __restrict__ logits,
                                                    float* __restrict__ G,
                                                    float* __restrict__ nuc,
                                                    float* __restrict__ cepart,
                                                    int* __restrict__ flags,
                                                    float* __restrict__ out) {
  int* gramdone = flags;            // 64
  int* gallf    = flags + 64;       // 16
  int* nflag    = flags + 80;       // 64
  int* ceflag   = flags + 144;      // 64

  __shared__ __align__(16) short Yb[DIM * DIM];
  __shared__ __align__(16) short Mh[DIM * DIM];
  __shared__ __align__(16) short Ml[DIM * DIM];
  __shared__ __align__(16) short Zb[DIM * DIM];
  __shared__ int cnt;

  const int bid  = blockIdx.x;
  const int tid  = threadIdx.x;
  const int lane = tid & 63;
  const int quad = lane >> 4;
  const int wv   = tid >> 6;    // 0..7

  float* Gall = G + (size_t)NCLS * DIM * DIM;

  // ---------------- CE blocks (65..128): 512 waves total ----------------
  if (bid > NCLS && bid <= NCLS + NB_CE) {
    const int gwave = (bid - NCLS - 1) * 8 + wv;
    float acc = 0.f;
    for (int row = gwave; row < N_ROWS; row += 512) {
      float v = logits[row * NCLS + lane];
      float mx = v;
      for (int off = 32; off > 0; off >>= 1) mx = fmaxf(mx, __shfl_xor(mx, off, 64));
      float e = expf(v - mx);
      for (int off = 32; off > 0; off >>= 1) e += __shfl_xor(e, off, 64);
      if (lane == 0) {
        int t = y[row];
        acc += (mx + logf(e)) - logits[row * NCLS + t];
      }
    }
    if (lane == 0) cepart[gwave] = acc;
    __syncthreads();
    if (tid == 0) flag_set(&ceflag[bid - NCLS - 1]);
    return;
  }

  // ---------------- builder blocks (129..144) ----------------
  if (bid > NCLS + NB_CE) {
    const int gb = bid - (NCLS + 1 + NB_CE);        // 0..15
    if (tid < NCLS) flag_wait(&gramdone[tid]);      // one flag per lane
    __syncthreads();
    if (tid < 256) {
      const int idx4 = gb * 256 + tid;              // 16 x 256 = 4096 float4s
      const float4* G4 = (const float4*)G;
      float4 s = make_float4(0.f, 0.f, 0.f, 0.f);
#pragma unroll 8
      for (int c = 0; c < NCLS; ++c) {
        float4 v = G4[(size_t)c * (DIM * DIM / 4) + idx4];
        s.x += v.x; s.y += v.y; s.z += v.z; s.w += v.w;
      }
      ((float4*)Gall)[idx4] = s;
    }
    __syncthreads();
    if (tid == 0) flag_set(&gallf[gb]);
    return;
  }

  // ====================== gram + NS blocks (0..64) ======================
  // 512 threads = 16x32 grid; thread owns 8x4 patch (i0..i0+7, j0..j0+3)
  const int ti = tid >> 5, tj = tid & 31;
  const int i0 = ti * 8,  j0 = tj * 4;

  float tpart = 0.f, fpart = 0.f;
  float4 gs[8];        // block 64 only: Gall slice (NS anchor)
  float  accg[8][4];   // class only: fp32 G_c patch (NS anchor)

  if (bid < NCLS) {
    // ---- ballot-compacted row list (one lane-0 atomicAdd per 64 rows) ----
    int* list = (int*)Yb;                       // up to 8192 ints (= Yb)
    if (tid == 0) cnt = 0;
    __syncthreads();
#pragma unroll
    for (int t = 0; t < 16; ++t) {
      int row = t * 512 + tid;
      bool hit = (y[row] == bid);
      unsigned long long m = __ballot(hit);
      int base = 0;
      if (lane == 0 && m) base = atomicAdd(&cnt, __popcll(m));
      base = __shfl(base, 0, 64);
      if (hit) {
        int pre = __popcll(m & ((1ull << lane) - 1ull));
        list[base + pre] = row;
      }
    }
    __syncthreads();
    const int n = cnt;

    // ---- pipelined gram: xs ping-pong (2 x 16 x 128 f32 = 16 KB in Mh),
    //      issue chunk k+1 loads before computing chunk k, 1 barrier/chunk.
    float (*xs)[DIM] = (float (*)[DIM])Mh;      // [2*16][128]

#pragma unroll
    for (int a = 0; a < 8; ++a)
#pragma unroll
      for (int b = 0; b < 4; ++b) accg[a][b] = 0.f;

    {   // prologue: stage chunk 0 into buffer 0
      float4 v = make_float4(0.f, 0.f, 0.f, 0.f);
      if (ti < n) v = *(const float4*)(feat + (size_t)list[ti] * DIM + j0);
      *(float4*)(&xs[ti][j0]) = v;
    }
    __syncthreads();

    int buf = 0;
    for (int base = 0; base < n; base += 16, buf ^= 1) {
      // issue next chunk's load (latency hides under the FMA block below)
      int li = base + 16 + ti;
      float4 vn = make_float4(0.f, 0.f, 0.f, 0.f);
      if (li < n) vn = *(const float4*)(feat + (size_t)list[li] * DIM + j0);
      // compute current chunk from xs[buf]
#pragma unroll
      for (int rw = 0; rw < 16; ++rw) {
        float xi[8], xj[4];
#pragma unroll
        for (int a = 0; a < 8; ++a) xi[a] = xs[buf * 16 + rw][i0 + a];
#pragma unroll
        for (int b = 0; b < 4; ++b) xj[b] = xs[buf * 16 + rw][j0 + b];
#pragma unroll
        for (int a = 0; a < 8; ++a)
#pragma unroll
          for (int b = 0; b < 4; ++b) accg[a][b] = fmaf(xi[a], xj[b], accg[a][b]);
      }
      // stage next chunk into the other buffer (no reader until after barrier)
      *(float4*)(&xs[(buf ^ 1) * 16 + ti][j0]) = vn;
      __syncthreads();
    }

    // stats + store G_c (plain stores; flag pattern proven by cepart/nuc)
    float* Gc = G + (size_t)bid * DIM * DIM;
#pragma unroll
    for (int a = 0; a < 8; ++a) {
      float4 row;
      float* rp = (float*)&row;
#pragma unroll
      for (int b = 0; b < 4; ++b) {
        float g = accg[a][b];
        rp[b] = g;
        fpart += g * g;
        if (i0 + a == j0 + b) tpart += g;
      }
      *(float4*)(Gc + (size_t)(i0 + a) * DIM + j0) = row;
    }
    __syncthreads();   // all threads' stores drained (vmcnt0 at barrier)
    if (tid == 0) flag_set(&gramdone[bid]);
    // list (Yb) / xs (Mh) dead from here.
  } else {
    // ---- block 64: wait for builders, load Gall ----
    if (tid < NB_BLD) flag_wait(&gallf[tid]);   // one flag per lane
    __syncthreads();
    const float4* Gm4 = (const float4*)Gall;
#pragma unroll
    for (int t = 0; t < 8; ++t) {
      int idx4 = tid + 512 * t;
      float4 v = Gm4[idx4];
      gs[t] = v;
      fpart += v.x * v.x + v.y * v.y + v.z * v.z + v.w * v.w;
      int flat = idx4 * 4, i = flat >> 7, jj = flat & 127;
      if (jj <= i && i < jj + 4) tpart += ((const float*)&v)[i - jj];
    }
  }

  // ---- reduce trace / fro2 across 8 waves ----
  for (int off = 32; off > 0; off >>= 1) {
    tpart += __shfl_down(tpart, off, 64);
    fpart += __shfl_down(fpart, off, 64);
  }
  float* redf = (float*)Zb;           // Zb not yet initialized
  if (lane == 0) { redf[wv] = tpart; redf[8 + wv] = fpart; }
  __syncthreads();
  float trace = 0.f, fro2 = 0.f;
#pragma unroll
  for (int w = 0; w < 8; ++w) { trace += redf[w]; fro2 += redf[8 + w]; }
  __syncthreads();                    // redf reads done -> Zb reusable

  float s = sqrtf(fro2);
  if (s < 1e-12f) s = 1.f;
  const float invs = 1.f / s;
  const float eps  = EPSN * trace * invs;

  // ---- init: Y0 = G/s + eps*I (single bf16), Z0 = I ----
  if (bid < NCLS) {
#pragma unroll
    for (int a = 0; a < 8; ++a) {
      int i = i0 + a;
      s16x4 vh;
#pragma unroll
      for (int b = 0; b < 4; ++b) {
        float x = accg[a][b] * invs + ((i == j0 + b) ? eps : 0.f);
        vh[b] = (short)f2bf(x);
      }
      *(s16x4*)(Yb + swz_idx(i, j0)) = vh;
    }
  } else {
#pragma unroll
    for (int t = 0; t < 8; ++t) {
      int idx4 = tid + 512 * t;
      int flat = idx4 * 4, i = flat >> 7, jj = flat & 127;
      s16x4 vh;
#pragma unroll
      for (int e = 0; e < 4; ++e) {
        float x = ((const float*)&gs[t])[e] * invs + ((i == jj + e) ? eps : 0.f);
        vh[e] = (short)f2bf(x);
      }
      *(s16x4*)(Yb + swz_idx(i, jj)) = vh;
    }
  }
  for (int grp = tid; grp < DIM * 16; grp += 512) {
    int i = grp >> 4, g = grp & 15;
    s16x8 v = (s16x8)0;
    if ((i >> 3) == g) v[i & 7] = (short)0x3F80;   // 1.0 bf16
    *(s16x8*)(Zb + i * 128 + ((g ^ (i & 15)) << 3)) = v;
  }
  __syncthreads();

  // 8 waves: 2x4 wave grid, each wave owns a 64x32 output tile (4x2 frags)
  const int wr = wv >> 2;     // 0..1 -> tile-rows 4*wr..4*wr+3
  const int wc = wv & 3;      // 0..3 -> tile-cols 2*wc..2*wc+1

  // ======== main loop: it = 0..NITER-2, branch-free R18 body ========
  for (int it = 0; it < NITER - 1; ++it) {
    const float kA = NS_C1[it];
    const float kB = NS_C2[it];

    // --- (a) W = Z*Y ---
    f32x4 acc[4][2];
#pragma unroll
    for (int r = 0; r < 4; ++r)
#pragma unroll
      for (int c2 = 0; c2 < 2; ++c2) acc[r][c2] = (f32x4)0.f;
#pragma unroll
    for (int ks = 0; ks < 4; ++ks) {
      s16x8 a[4], b[2];
#pragma unroll
      for (int r = 0; r < 4; ++r) a[r] = load_frag(Zb, (4 * wr + r) * 16, ks, lane);
#pragma unroll
      for (int c2 = 0; c2 < 2; ++c2) b[c2] = load_frag(Yb, (2 * wc + c2) * 16, ks, lane);
#pragma unroll
      for (int r = 0; r < 4; ++r)
#pragma unroll
        for (int c2 = 0; c2 < 2; ++c2)
          acc[r][c2] = __builtin_amdgcn_mfma_f32_16x16x32_bf16(a[r], b[c2], acc[r][c2], 0, 0, 0);
    }
    // --- (b) M = kA*I - kB*W, clamp, hi/lo split, transposed store ---
#pragma unroll
    for (int r = 0; r < 4; ++r) {
      int ibase = (4 * wr + r) * 16 + quad * 4;
      int cg    = ibase >> 3;
#pragma unroll
      for (int c2 = 0; c2 < 2; ++c2) {
        int jg  = (2 * wc + c2) * 16 + (lane & 15);
        int idx = jg * 128 + ((cg ^ (jg & 15)) << 3) + (ibase & 7);
        s16x4 vh, vl;
#pragma unroll
        for (int e = 0; e < 4; ++e) {
          float mv = -kB * acc[r][c2][e] + ((ibase + e == jg) ? kA : 0.f);
          mv = fminf(fmaxf(mv, -4.f), 4.f);
          unsigned short hh = f2bf(mv);
          vh[e] = (short)hh;
          vl[e] = (short)f2bf(mv - bf2f(hh));
        }
        *(s16x4*)(Mh + idx) = vh;
        *(s16x4*)(Ml + idx) = vl;
      }
    }
    __syncthreads();

    // --- (c) Y' = M*Y, Z' = M*Z (M = shared split-A; iterates commute) ---
    f32x4 ay[4][2], az[4][2];
#pragma unroll
    for (int r = 0; r < 4; ++r)
#pragma unroll
      for (int c2 = 0; c2 < 2; ++c2) { ay[r][c2] = (f32x4)0.f; az[r][c2] = (f32x4)0.f; }
#pragma unroll
    for (int ks = 0; ks < 4; ++ks) {
      s16x8 aMh[4], aMl[4], bY[2], bZ[2];
#pragma unroll
      for (int r = 0; r < 4; ++r) {
        int rb = (4 * wr + r) * 16;
        aMh[r] = load_frag(Mh, rb, ks, lane);
        aMl[r] = load_frag(Ml, rb, ks, lane);
      }
#pragma unroll
      for (int c2 = 0; c2 < 2; ++c2) {
        int cb = (2 * wc + c2) * 16;
        bY[c2] = load_frag(Yb, cb, ks, lane);
        bZ[c2] = load_frag(Zb, cb, ks, lane);
      }
#pragma unroll
      for (int r = 0; r < 4; ++r)
#pragma unroll
        for (int c2 = 0; c2 < 2; ++c2) {
          ay[r][c2] = __builtin_amdgcn_mfma_f32_16x16x32_bf16(aMh[r], bY[c2], ay[r][c2], 0, 0, 0);
          ay[r][c2] = __builtin_amdgcn_mfma_f32_16x16x32_bf16(aMl[r], bY[c2], ay[r][c2], 0, 0, 0);
          az[r][c2] = __builtin_amdgcn_mfma_f32_16x16x32_bf16(aMh[r], bZ[c2], az[r][c2], 0, 0, 0);
          az[r][c2] = __builtin_amdgcn_mfma_f32_16x16x32_bf16(aMl[r], bZ[c2], az[r][c2], 0, 0, 0);
        }
    }
    __syncthreads();

    // --- (d) store Y' (single), Z' (single), transposed ---
#pragma unroll
    for (int r = 0; r < 4; ++r) {
      int ibase = (4 * wr + r) * 16 + quad * 4;
      int cg    = ibase >> 3;
#pragma unroll
      for (int c2 = 0; c2 < 2; ++c2) {
        int jg  = (2 * wc + c2) * 16 + (lane & 15);
        int idx = jg * 128 + ((cg ^ (jg & 15)) << 3) + (ibase & 7);
        s16x4 vy, vz;
#pragma unroll
        for (int e = 0; e < 4; ++e) {
          vy[e] = (short)f2bf(ay[r][c2][e]);
          vz[e] = (short)f2bf(az[r][c2][e]);
        }
        *(s16x4*)(Yb + idx) = vy;
        *(s16x4*)(Zb + idx) = vz;
      }
    }
    __syncthreads();
  }

  // ======== peeled final iteration: Z' = M*Z only (Y dead) ========
  {
    const float kA = NS_C1[NITER - 1];
    const float kB = NS_C2[NITER - 1];

    // --- (a) W = Z*Y ---
    f32x4 acc[4][2];
#pragma unroll
    for (int r = 0; r < 4; ++r)
#pragma unroll
      for (int c2 = 0; c2 < 2; ++c2) acc[r][c2] = (f32x4)0.f;
#pragma unroll
    for (int ks = 0; ks < 4; ++ks) {
      s16x8 a[4], b[2];
#pragma unroll
      for (int r = 0; r < 4; ++r) a[r] = load_frag(Zb, (4 * wr + r) * 16, ks, lane);
#pragma unroll
      for (int c2 = 0; c2 < 2; ++c2) b[c2] = load_frag(Yb, (2 * wc + c2) * 16, ks, lane);
#pragma unroll
      for (int r = 0; r < 4; ++r)
#pragma unroll
        for (int c2 = 0; c2 < 2; ++c2)
          acc[r][c2] = __builtin_amdgcn_mfma_f32_16x16x32_bf16(a[r], b[c2], acc[r][c2], 0, 0, 0);
    }
    // --- (b) M = kA*I - kB*W ---
#pragma unroll
    for (int r = 0; r < 4; ++r) {
      int ibase = (4 * wr + r) * 16 + quad * 4;
      int cg    = ibase >> 3;
#pragma unroll
      for (int c2 = 0; c2 < 2; ++c2) {
        int jg  = (2 * wc + c2) * 16 + (lane & 15);
        int idx = jg * 128 + ((cg ^ (jg & 15)) << 3) + (ibase & 7);
        s16x4 vh, vl;
#pragma unroll
        for (int e = 0; e < 4; ++e) {
          float mv = -kB * acc[r][c2][e] + ((ibase + e == jg) ? kA : 0.f);
          mv = fminf(fmaxf(mv, -4.f), 4.f);
          unsigned short hh = f2bf(mv);
          vh[e] = (short)hh;
          vl[e] = (short)f2bf(mv - bf2f(hh));
        }
        *(s16x4*)(Mh + idx) = vh;
        *(s16x4*)(Ml + idx) = vl;
      }
    }
    __syncthreads();

    // --- (c) Z' = M*Z only ---
    f32x4 az[4][2];
#pragma unroll
    for (int r = 0; r < 4; ++r)
#pragma unroll
      for (int c2 = 0; c2 < 2; ++c2) az[r][c2] = (f32x4)0.f;
#pragma unroll
    for (int ks = 0; ks < 4; ++ks) {
      s16x8 aMh[4], aMl[4], bZ[2];
#pragma unroll
      for (int r = 0; r < 4; ++r) {
        int rb = (4 * wr + r) * 16;
        aMh[r] = load_frag(Mh, rb, ks, lane);
        aMl[r] = load_frag(Ml, rb, ks, lane);
      }
#pragma unroll
      for (int c2 = 0; c2 < 2; ++c2)
        bZ[c2] = load_frag(Zb, (2 * wc + c2) * 16, ks, lane);
#pragma unroll
      for (int r = 0; r < 4; ++r)
#pragma unroll
        for (int c2 = 0; c2 < 2; ++c2) {
          az[r][c2] = __builtin_amdgcn_mfma_f32_16x16x32_bf16(aMh[r], bZ[c2], az[r][c2], 0, 0, 0);
          az[r][c2] = __builtin_amdgcn_mfma_f32_16x16x32_bf16(aMl[r], bZ[c2], az[r][c2], 0, 0, 0);
        }
    }
    __syncthreads();

    // --- (d) store Z' only ---
#pragma unroll
    for (int r = 0; r < 4; ++r) {
      int ibase = (4 * wr + r) * 16 + quad * 4;
      int cg    = ibase >> 3;
#pragma unroll
      for (int c2 = 0; c2 < 2; ++c2) {
        int jg  = (2 * wc + c2) * 16 + (lane & 15);
        int idx = jg * 128 + ((cg ^ (jg & 15)) << 3) + (ibase & 7);
        s16x4 vz;
#pragma unroll
        for (int e = 0; e < 4; ++e) vz[e] = (short)f2bf(az[r][c2][e]);
        *(s16x4*)(Zb + idx) = vz;
      }
    }
    __syncthreads();
  }

  // ---- traces: tr(GZ) (fp32 anchor in regs), tr(Z), tr(Z^3) ----
  float t_gz = 0.f, t_z = 0.f, t_z3 = 0.f;
  if (bid < NCLS) {
#pragma unroll
    for (int a = 0; a < 8; ++a) {
      s16x4 zv = *(const s16x4*)(Zb + swz_idx(i0 + a, j0));
#pragma unroll
      for (int b = 0; b < 4; ++b) t_gz += accg[a][b] * bf2f((unsigned short)zv[b]);
    }
  } else {
#pragma unroll
    for (int t = 0; t < 8; ++t) {
      int idx4 = tid + 512 * t;
      int flat = idx4 * 4, i = flat >> 7, jj = flat & 127;
      s16x4 zv = *(const s16x4*)(Zb + swz_idx(i, jj));
#pragma unroll
      for (int e = 0; e < 4; ++e) t_gz += ((const float*)&gs[t])[e] * bf2f((unsigned short)zv[e]);
    }
  }
  if (tid < DIM) t_z = bf2f((unsigned short)Zb[swz_idx(tid, tid)]);

  {  // U = Z*Z tile-wise; tr(Z^3) = sum U_ij * Z_ji
    f32x4 u[4][2];
#pragma unroll
    for (int r = 0; r < 4; ++r)
#pragma unroll
      for (int c2 = 0; c2 < 2; ++c2) u[r][c2] = (f32x4)0.f;
#pragma unroll
    for (int ks = 0; ks < 4; ++ks) {
      s16x8 a[4], b[2];
#pragma unroll
      for (int r = 0; r < 4; ++r) a[r] = load_frag(Zb, (4 * wr + r) * 16, ks, lane);
#pragma unroll
      for (int c2 = 0; c2 < 2; ++c2) b[c2] = load_frag(Zb, (2 * wc + c2) * 16, ks, lane);
#pragma unroll
      for (int r = 0; r < 4; ++r)
#pragma unroll
        for (int c2 = 0; c2 < 2; ++c2)
          u[r][c2] = __builtin_amdgcn_mfma_f32_16x16x32_bf16(a[r], b[c2], u[r][c2], 0, 0, 0);
    }
#pragma unroll
    for (int r = 0; r < 4; ++r) {
      int ibase = (4 * wr + r) * 16 + quad * 4;
      int cg    = ibase >> 3;
#pragma unroll
      for (int c2 = 0; c2 < 2; ++c2) {
        int jg  = (2 * wc + c2) * 16 + (lane & 15);
        int idx = jg * 128 + ((cg ^ (jg & 15)) << 3) + (ibase & 7);
        s16x4 zt = *(const s16x4*)(Zb + idx);
#pragma unroll
        for (int e = 0; e < 4; ++e) t_z3 += u[r][c2][e] * bf2f((unsigned short)zt[e]);
      }
    }
  }

  for (int off = 32; off > 0; off >>= 1) {
    t_gz += __shfl_down(t_gz, off, 64);
    t_z  += __shfl_down(t_z,  off, 64);
    t_z3 += __shfl_down(t_z3, off, 64);
  }
  __syncthreads();
  float* red = (float*)Mh;             // Mh dead after last iter
  if (lane == 0) { red[wv] = t_gz; red[8 + wv] = t_z; red[16 + wv] = t_z3; }
  __syncthreads();

  float nuc_own = 0.f;
  if (tid == 0) {
    float gz = 0.f, z1 = 0.f, z3 = 0.f;
#pragma unroll
    for (int w = 0; w < 8; ++w) { gz += red[w]; z1 += red[8 + w]; z3 += red[16 + w]; }
    float trsq = gz * invs + 0.5f * eps * z1 - 0.125f * eps * eps * z3;
    nuc_own = sqrtf(s) * trsq;
    nuc[bid] = nuc_own;
  }

  if (bid < NCLS) {
    if (tid == 0) flag_set(&nflag[bid]);
    return;
  }

  // ======== block 64: final combine (parallel poll, one flag/lane) ========
  if (tid < NCLS)          flag_wait(&nflag[tid]);
  else if (tid < 2 * NCLS) flag_wait(&ceflag[tid - NCLS]);
  __syncthreads();

  float ce2 = cepart[tid];                       // 512 entries, 512 threads
  float vmx = (tid < NCLS) ? fmaxf(nuc[tid], DELTA_) : 0.f;
  for (int off = 32; off > 0; off >>= 1) {
    vmx += __shfl_down(vmx, off, 64);
    ce2 += __shfl_down(ce2, off, 64);
  }
  if (lane == 0) { red[wv] = vmx; red[8 + wv] = ce2; }
  __syncthreads();
  if (tid == 0) {
    float vs = 0.f, cs = 0.f;
#pragma unroll
    for (int w = 0; w < 8; ++w) { vs += red[w]; cs += red[8 + w]; }
    float ole = (vs - nuc_own) * (LAMBDA_ / (float)N_ROWS);
    out[0] = ole + cs / (float)N_ROWS;
  }
}

extern "C" void kernel_launch(void* const* d_in, const int* in_sizes, int n_in,
                              void* d_out, int out_size, void* d_ws, size_t ws_size,
                              hipStream_t stream) {
  const float* logits = (const float*)d_in[0];   // out  [8192,64]
  const float* feat   = (const float*)d_in[1];   // feat [8192,128]
  const int*   yp     = (const int*)d_in[2];     // y    [8192]

  int*   flags  = (int*)d_ws;                    // 256 ints (208 used)
  float* nuc    = (float*)d_ws + 256;            // 68
  float* cepart = nuc + 68;                      // 512
  float* G      = cepart + 512;                  // 65 x 16384 (Gall = idx 64)

  // Zero the flag region (workspace is poisoned each run; keeps flag
  // semantics independent of harness re-poison timing). Graph-capture-safe.
  hipMemsetAsync(d_ws, 0, 256 * sizeof(int), stream);

  ole_fused<<<NCLS + 1 + NB_CE + NB_BLD, 512, 0, stream>>>(
      feat, yp, logits, G, nuc, cepart, flags, (float*)d_out);
}

// Round 9
// 120.003 us; speedup vs baseline: 1.1681x; 1.0454x over previous
//
#include <hip/hip_runtime.h>
#include <math.h>

// OLE loss on MI355X — FUSED single kernel, R24.
// ||X_c||* = trace(sqrt(G_c)), G_c = X_c^T X_c (128x128).
// R24 = R23 (best: 69.7us dispatch / 125.5 bench) with the NS iteration's
// hi/lo M split replaced by the RESIDUAL FORM  M = I + D,  D = M - I:
//   Y' = M*Y = Y + D*Y  (C-init the MFMA accumulator with the Y fragment
//   read at the transposed-store index — symmetric matrices make that one
//   ds_read_b64 per tile). Why valid: hi/lo existed because bf16 rounds
//   M's ~1.0 diagonal at 4e-3 absolute (comparable to the late-iteration
//   correction itself — R4). D is SMALL near convergence (|D|<=1e-3 at the
//   last iters), so single-bf16 D has ~2e-6 absolute error there — better
//   than hi/lo's 7e-6 precisely where accuracy is decided; early-iter D~O(1)
//   errors are self-corrected by the NS contraction (Y/Z are already
//   single-bf16 state each iteration).
// Effect/iter/wave: phase (c) A-reads 32->16 b128, MFMA 128->64; phase (b)
// writes 16->8; Ml buffer deleted (LDS 136->104KB). CU-wide LDS-pipe time
// ~8.4K->~5.8K cy/iter (LDS traffic is tiling-invariant — re-derived:
// reads/ks = 2(R/16)+P(C/16) min = 12 for all wave decompositions — so
// operand-count reduction is the only LDS lever left; reg-caching spills,
// R20).
// Kept: pipelined gram (R23), peeled final Z-only step (R22; guard-in-loop
// cost 14us — R21), builders tree-sum Gall (R16), ballot list, flags,
// 512t/8-wave/4x2-frag engine (1024t pins VGPR=64 — R16/R17).
// Lessons: R8 (grid.sync ~50us), R11 (one flag/lane), R14+R21 (NITER=6:
// |w-1|<=1e-5 by k6), R17/R21 (bank conflicts NS-internal, scale w/ reads).

#define N_ROWS 8192
#define DIM    128
#define NCLS   64
#define NB_CE  64
#define NB_BLD 16
#define NITER  6
#define EPSN   2e-4f
#define LAMBDA_ 0.25f
#define DELTA_  1.0f
#define MAGIC  0x13579BDF   // != 0xAAAAAAAA poison, != 0

typedef __attribute__((ext_vector_type(8))) short s16x8;  // 8 bf16 = 4 VGPR
typedef __attribute__((ext_vector_type(4))) short s16x4;  // 4 bf16
typedef __attribute__((ext_vector_type(4))) float f32x4;

// Scaled-NS ladder: M_k = C1[k]*I - C2[k]*W, C1 = 1.5*sqrt(t), C2 = 0.5*t^1.5.
// t-schedule {2.9, 2.758, 2.13, 1.868, 1.264, 1}; |w-1|<=1e-5 after step 6.
static __device__ const float NS_C1[NITER] =
  {2.554408f, 2.491084f, 2.189178f, 2.050122f, 1.686417f, 1.5f};
static __device__ const float NS_C2[NITER] =
  {2.469261f, 2.290137f, 1.554316f, 1.276543f, 0.710544f, 0.5f};

__device__ __forceinline__ unsigned short f2bf(float f) {   // RNE
  unsigned u = __float_as_uint(f);
  u = (u + 0x7FFFu + ((u >> 16) & 1u)) >> 16;
  return (unsigned short)u;
}
__device__ __forceinline__ float bf2f(unsigned short h) {
  return __uint_as_float(((unsigned)h) << 16);
}

// bf16 LDS: element (i,j) at short-index i*128 + (((j>>3)^(i&15))<<3) + (j&7)
__device__ __forceinline__ int swz_idx(int i, int j) {
  return i * 128 + (((j >> 3) ^ (i & 15)) << 3) + (j & 7);
}

__device__ __forceinline__ s16x8 load_frag(const short* buf, int row0,
                                           int kstep, int lane) {
  int m  = row0 + (lane & 15);
  int kg = kstep * 4 + (lane >> 4);
  return *(const s16x8*)(buf + m * 128 + ((kg ^ (m & 15)) << 3));
}

__device__ __forceinline__ void flag_set(int* p) {
  __threadfence();
  __hip_atomic_store(p, MAGIC, __ATOMIC_RELEASE, __HIP_MEMORY_SCOPE_AGENT);
}
__device__ __forceinline__ void flag_wait(const int* p) {
  while (__hip_atomic_load(p, __ATOMIC_ACQUIRE, __HIP_MEMORY_SCOPE_AGENT) != MAGIC)
    __builtin_amdgcn_s_sleep(8);
}

// ---------------------------------------------------------------------------
// Fused kernel: 145 blocks x 512 threads (8 waves, 2/SIMD, VGPR <=128).
//  0..63   : ballot list -> pipelined LDS-staged Gram -> store G_c ->
//            gramdone -> NS(G_c, reg anchor) -> nuc[c] -> nflag
//  64      : wait gallf[16] -> load Gall -> NS -> wait nflag/ceflag -> out
//  65..128 : CE (512 waves total) -> cepart -> ceflag
//  129..144: wait gramdone[64] -> tree-sum G_c slice -> Gall -> gallf
// ---------------------------------------------------------------------------
__global__ __launch_bounds__(512, 1) void ole_fused(const float* __restrict__ feat,
                                                    const int* __restrict__ y,
                                                    const float* __restrict__ logits,
                                                    float* __restrict__ G,
                                                    float* __restrict__ nuc,
                                                    float* __restrict__ cepart,
                                                    int* __restrict__ flags,
                                                    float* __restrict__ out) {
  int* gramdone = flags;            // 64
  int* gallf    = flags + 64;       // 16
  int* nflag    = flags + 80;       // 64
  int* ceflag   = flags + 144;      // 64

  __shared__ __align__(16) short Yb[DIM * DIM];
  __shared__ __align__(16) short Db[DIM * DIM];   // D = M - I (single bf16)
  __shared__ __align__(16) short Zb[DIM * DIM];
  __shared__ int cnt;

  const int bid  = blockIdx.x;
  const int tid  = threadIdx.x;
  const int lane = tid & 63;
  const int quad = lane >> 4;
  const int wv   = tid >> 6;    // 0..7

  float* Gall = G + (size_t)NCLS * DIM * DIM;

  // ---------------- CE blocks (65..128): 512 waves total ----------------
  if (bid > NCLS && bid <= NCLS + NB_CE) {
    const int gwave = (bid - NCLS - 1) * 8 + wv;
    float acc = 0.f;
    for (int row = gwave; row < N_ROWS; row += 512) {
      float v = logits[row * NCLS + lane];
      float mx = v;
      for (int off = 32; off > 0; off >>= 1) mx = fmaxf(mx, __shfl_xor(mx, off, 64));
      float e = expf(v - mx);
      for (int off = 32; off > 0; off >>= 1) e += __shfl_xor(e, off, 64);
      if (lane == 0) {
        int t = y[row];
        acc += (mx + logf(e)) - logits[row * NCLS + t];
      }
    }
    if (lane == 0) cepart[gwave] = acc;
    __syncthreads();
    if (tid == 0) flag_set(&ceflag[bid - NCLS - 1]);
    return;
  }

  // ---------------- builder blocks (129..144) ----------------
  if (bid > NCLS + NB_CE) {
    const int gb = bid - (NCLS + 1 + NB_CE);        // 0..15
    if (tid < NCLS) flag_wait(&gramdone[tid]);      // one flag per lane
    __syncthreads();
    if (tid < 256) {
      const int idx4 = gb * 256 + tid;              // 16 x 256 = 4096 float4s
      const float4* G4 = (const float4*)G;
      float4 s = make_float4(0.f, 0.f, 0.f, 0.f);
#pragma unroll 8
      for (int c = 0; c < NCLS; ++c) {
        float4 v = G4[(size_t)c * (DIM * DIM / 4) + idx4];
        s.x += v.x; s.y += v.y; s.z += v.z; s.w += v.w;
      }
      ((float4*)Gall)[idx4] = s;
    }
    __syncthreads();
    if (tid == 0) flag_set(&gallf[gb]);
    return;
  }

  // ====================== gram + NS blocks (0..64) ======================
  // 512 threads = 16x32 grid; thread owns 8x4 patch (i0..i0+7, j0..j0+3)
  const int ti = tid >> 5, tj = tid & 31;
  const int i0 = ti * 8,  j0 = tj * 4;

  float tpart = 0.f, fpart = 0.f;
  float4 gs[8];        // block 64 only: Gall slice (NS anchor)
  float  accg[8][4];   // class only: fp32 G_c patch (NS anchor)

  if (bid < NCLS) {
    // ---- ballot-compacted row list (one lane-0 atomicAdd per 64 rows) ----
    int* list = (int*)Yb;                       // up to 8192 ints (= Yb)
    if (tid == 0) cnt = 0;
    __syncthreads();
#pragma unroll
    for (int t = 0; t < 16; ++t) {
      int row = t * 512 + tid;
      bool hit = (y[row] == bid);
      unsigned long long m = __ballot(hit);
      int base = 0;
      if (lane == 0 && m) base = atomicAdd(&cnt, __popcll(m));
      base = __shfl(base, 0, 64);
      if (hit) {
        int pre = __popcll(m & ((1ull << lane) - 1ull));
        list[base + pre] = row;
      }
    }
    __syncthreads();
    const int n = cnt;

    // ---- pipelined gram: xs ping-pong (2 x 16 x 128 f32 = 16 KB in Db),
    //      issue chunk k+1 loads before computing chunk k, 1 barrier/chunk.
    float (*xs)[DIM] = (float (*)[DIM])Db;      // [2*16][128]

#pragma unroll
    for (int a = 0; a < 8; ++a)
#pragma unroll
      for (int b = 0; b < 4; ++b) accg[a][b] = 0.f;

    {   // prologue: stage chunk 0 into buffer 0
      float4 v = make_float4(0.f, 0.f, 0.f, 0.f);
      if (ti < n) v = *(const float4*)(feat + (size_t)list[ti] * DIM + j0);
      *(float4*)(&xs[ti][j0]) = v;
    }
    __syncthreads();

    int buf = 0;
    for (int base = 0; base < n; base += 16, buf ^= 1) {
      // issue next chunk's load (latency hides under the FMA block below)
      int li = base + 16 + ti;
      float4 vn = make_float4(0.f, 0.f, 0.f, 0.f);
      if (li < n) vn = *(const float4*)(feat + (size_t)list[li] * DIM + j0);
      // compute current chunk from xs[buf]
#pragma unroll
      for (int rw = 0; rw < 16; ++rw) {
        float xi[8], xj[4];
#pragma unroll
        for (int a = 0; a < 8; ++a) xi[a] = xs[buf * 16 + rw][i0 + a];
#pragma unroll
        for (int b = 0; b < 4; ++b) xj[b] = xs[buf * 16 + rw][j0 + b];
#pragma unroll
        for (int a = 0; a < 8; ++a)
#pragma unroll
          for (int b = 0; b < 4; ++b) accg[a][b] = fmaf(xi[a], xj[b], accg[a][b]);
      }
      // stage next chunk into the other buffer (no reader until after barrier)
      *(float4*)(&xs[(buf ^ 1) * 16 + ti][j0]) = vn;
      __syncthreads();
    }

    // stats + store G_c (plain stores; flag pattern proven by cepart/nuc)
    float* Gc = G + (size_t)bid * DIM * DIM;
#pragma unroll
    for (int a = 0; a < 8; ++a) {
      float4 row;
      float* rp = (float*)&row;
#pragma unroll
      for (int b = 0; b < 4; ++b) {
        float g = accg[a][b];
        rp[b] = g;
        fpart += g * g;
        if (i0 + a == j0 + b) tpart += g;
      }
      *(float4*)(Gc + (size_t)(i0 + a) * DIM + j0) = row;
    }
    __syncthreads();   // all threads' stores drained (vmcnt0 at barrier)
    if (tid == 0) flag_set(&gramdone[bid]);
    // list (Yb) / xs (Db) dead from here.
  } else {
    // ---- block 64: wait for builders, load Gall ----
    if (tid < NB_BLD) flag_wait(&gallf[tid]);   // one flag per lane
    __syncthreads();
    const float4* Gm4 = (const float4*)Gall;
#pragma unroll
    for (int t = 0; t < 8; ++t) {
      int idx4 = tid + 512 * t;
      float4 v = Gm4[idx4];
      gs[t] = v;
      fpart += v.x * v.x + v.y * v.y + v.z * v.z + v.w * v.w;
      int flat = idx4 * 4, i = flat >> 7, jj = flat & 127;
      if (jj <= i && i < jj + 4) tpart += ((const float*)&v)[i - jj];
    }
  }

  // ---- reduce trace / fro2 across 8 waves ----
  for (int off = 32; off > 0; off >>= 1) {
    tpart += __shfl_down(tpart, off, 64);
    fpart += __shfl_down(fpart, off, 64);
  }
  float* redf = (float*)Zb;           // Zb not yet initialized
  if (lane == 0) { redf[wv] = tpart; redf[8 + wv] = fpart; }
  __syncthreads();
  float trace = 0.f, fro2 = 0.f;
#pragma unroll
  for (int w = 0; w < 8; ++w) { trace += redf[w]; fro2 += redf[8 + w]; }
  __syncthreads();                    // redf reads done -> Zb reusable

  float s = sqrtf(fro2);
  if (s < 1e-12f) s = 1.f;
  const float invs = 1.f / s;
  const float eps  = EPSN * trace * invs;

  // ---- init: Y0 = G/s + eps*I (single bf16), Z0 = I ----
  if (bid < NCLS) {
#pragma unroll
    for (int a = 0; a < 8; ++a) {
      int i = i0 + a;
      s16x4 vh;
#pragma unroll
      for (int b = 0; b < 4; ++b) {
        float x = accg[a][b] * invs + ((i == j0 + b) ? eps : 0.f);
        vh[b] = (short)f2bf(x);
      }
      *(s16x4*)(Yb + swz_idx(i, j0)) = vh;
    }
  } else {
#pragma unroll
    for (int t = 0; t < 8; ++t) {
      int idx4 = tid + 512 * t;
      int flat = idx4 * 4, i = flat >> 7, jj = flat & 127;
      s16x4 vh;
#pragma unroll
      for (int e = 0; e < 4; ++e) {
        float x = ((const float*)&gs[t])[e] * invs + ((i == jj + e) ? eps : 0.f);
        vh[e] = (short)f2bf(x);
      }
      *(s16x4*)(Yb + swz_idx(i, jj)) = vh;
    }
  }
  for (int grp = tid; grp < DIM * 16; grp += 512) {
    int i = grp >> 4, g = grp & 15;
    s16x8 v = (s16x8)0;
    if ((i >> 3) == g) v[i & 7] = (short)0x3F80;   // 1.0 bf16
    *(s16x8*)(Zb + i * 128 + ((g ^ (i & 15)) << 3)) = v;
  }
  __syncthreads();

  // 8 waves: 2x4 wave grid, each wave owns a 64x32 output tile (4x2 frags)
  const int wr = wv >> 2;     // 0..1 -> tile-rows 4*wr..4*wr+3
  const int wc = wv & 3;      // 0..3 -> tile-cols 2*wc..2*wc+1

  // ======== main loop: it = 0..NITER-2 (full Y+Z update, D-form) ========
  for (int it = 0; it < NITER - 1; ++it) {
    const float kA = NS_C1[it];
    const float kB = NS_C2[it];

    // --- (a) W = Z*Y ---
    f32x4 acc[4][2];
#pragma unroll
    for (int r = 0; r < 4; ++r)
#pragma unroll
      for (int c2 = 0; c2 < 2; ++c2) acc[r][c2] = (f32x4)0.f;
#pragma unroll
    for (int ks = 0; ks < 4; ++ks) {
      s16x8 a[4], b[2];
#pragma unroll
      for (int r = 0; r < 4; ++r) a[r] = load_frag(Zb, (4 * wr + r) * 16, ks, lane);
#pragma unroll
      for (int c2 = 0; c2 < 2; ++c2) b[c2] = load_frag(Yb, (2 * wc + c2) * 16, ks, lane);
#pragma unroll
      for (int r = 0; r < 4; ++r)
#pragma unroll
        for (int c2 = 0; c2 < 2; ++c2)
          acc[r][c2] = __builtin_amdgcn_mfma_f32_16x16x32_bf16(a[r], b[c2], acc[r][c2], 0, 0, 0);
    }
    // --- (b) D = (kA-1)*I - kB*W, clamp, single bf16, transposed store ---
#pragma unroll
    for (int r = 0; r < 4; ++r) {
      int ibase = (4 * wr + r) * 16 + quad * 4;
      int cg    = ibase >> 3;
#pragma unroll
      for (int c2 = 0; c2 < 2; ++c2) {
        int jg  = (2 * wc + c2) * 16 + (lane & 15);
        int idx = jg * 128 + ((cg ^ (jg & 15)) << 3) + (ibase & 7);
        s16x4 vd;
#pragma unroll
        for (int e = 0; e < 4; ++e) {
          float dv = -kB * acc[r][c2][e] + ((ibase + e == jg) ? (kA - 1.f) : 0.f);
          dv = fminf(fmaxf(dv, -4.f), 4.f);
          vd[e] = (short)f2bf(dv);
        }
        *(s16x4*)(Db + idx) = vd;
      }
    }
    __syncthreads();

    // --- (c) Y' = Y + D*Y, Z' = Z + D*Z (C-init with Y/Z fragments) ---
    f32x4 ay[4][2], az[4][2];
#pragma unroll
    for (int r = 0; r < 4; ++r) {
      int ibase = (4 * wr + r) * 16 + quad * 4;
      int cg    = ibase >> 3;
#pragma unroll
      for (int c2 = 0; c2 < 2; ++c2) {
        int jg  = (2 * wc + c2) * 16 + (lane & 15);
        int idx = jg * 128 + ((cg ^ (jg & 15)) << 3) + (ibase & 7);
        s16x4 yv = *(const s16x4*)(Yb + idx);
        s16x4 zv = *(const s16x4*)(Zb + idx);
#pragma unroll
        for (int e = 0; e < 4; ++e) {
          ay[r][c2][e] = bf2f((unsigned short)yv[e]);
          az[r][c2][e] = bf2f((unsigned short)zv[e]);
        }
      }
    }
#pragma unroll
    for (int ks = 0; ks < 4; ++ks) {
      s16x8 aD[4], bY[2], bZ[2];
#pragma unroll
      for (int r = 0; r < 4; ++r)
        aD[r] = load_frag(Db, (4 * wr + r) * 16, ks, lane);
#pragma unroll
      for (int c2 = 0; c2 < 2; ++c2) {
        int cb = (2 * wc + c2) * 16;
        bY[c2] = load_frag(Yb, cb, ks, lane);
        bZ[c2] = load_frag(Zb, cb, ks, lane);
      }
#pragma unroll
      for (int r = 0; r < 4; ++r)
#pragma unroll
        for (int c2 = 0; c2 < 2; ++c2) {
          ay[r][c2] = __builtin_amdgcn_mfma_f32_16x16x32_bf16(aD[r], bY[c2], ay[r][c2], 0, 0, 0);
          az[r][c2] = __builtin_amdgcn_mfma_f32_16x16x32_bf16(aD[r], bZ[c2], az[r][c2], 0, 0, 0);
        }
    }
    __syncthreads();

    // --- (d) store Y' (single), Z' (single), transposed ---
#pragma unroll
    for (int r = 0; r < 4; ++r) {
      int ibase = (4 * wr + r) * 16 + quad * 4;
      int cg    = ibase >> 3;
#pragma unroll
      for (int c2 = 0; c2 < 2; ++c2) {
        int jg  = (2 * wc + c2) * 16 + (lane & 15);
        int idx = jg * 128 + ((cg ^ (jg & 15)) << 3) + (ibase & 7);
        s16x4 vy, vz;
#pragma unroll
        for (int e = 0; e < 4; ++e) {
          vy[e] = (short)f2bf(ay[r][c2][e]);
          vz[e] = (short)f2bf(az[r][c2][e]);
        }
        *(s16x4*)(Yb + idx) = vy;
        *(s16x4*)(Zb + idx) = vz;
      }
    }
    __syncthreads();
  }

  // ======== peeled final iteration: Z' = Z + D*Z only (Y dead) ========
  {
    const float kA = NS_C1[NITER - 1];
    const float kB = NS_C2[NITER - 1];

    // --- (a) W = Z*Y ---
    f32x4 acc[4][2];
#pragma unroll
    for (int r = 0; r < 4; ++r)
#pragma unroll
      for (int c2 = 0; c2 < 2; ++c2) acc[r][c2] = (f32x4)0.f;
#pragma unroll
    for (int ks = 0; ks < 4; ++ks) {
      s16x8 a[4], b[2];
#pragma unroll
      for (int r = 0; r < 4; ++r) a[r] = load_frag(Zb, (4 * wr + r) * 16, ks, lane);
#pragma unroll
      for (int c2 = 0; c2 < 2; ++c2) b[c2] = load_frag(Yb, (2 * wc + c2) * 16, ks, lane);
#pragma unroll
      for (int r = 0; r < 4; ++r)
#pragma unroll
        for (int c2 = 0; c2 < 2; ++c2)
          acc[r][c2] = __builtin_amdgcn_mfma_f32_16x16x32_bf16(a[r], b[c2], acc[r][c2], 0, 0, 0);
    }
    // --- (b) D = (kA-1)*I - kB*W ---
#pragma unroll
    for (int r = 0; r < 4; ++r) {
      int ibase = (4 * wr + r) * 16 + quad * 4;
      int cg    = ibase >> 3;
#pragma unroll
      for (int c2 = 0; c2 < 2; ++c2) {
        int jg  = (2 * wc + c2) * 16 + (lane & 15);
        int idx = jg * 128 + ((cg ^ (jg & 15)) << 3) + (ibase & 7);
        s16x4 vd;
#pragma unroll
        for (int e = 0; e < 4; ++e) {
          float dv = -kB * acc[r][c2][e] + ((ibase + e == jg) ? (kA - 1.f) : 0.f);
          dv = fminf(fmaxf(dv, -4.f), 4.f);
          vd[e] = (short)f2bf(dv);
        }
        *(s16x4*)(Db + idx) = vd;
      }
    }
    __syncthreads();

    // --- (c) Z' = Z + D*Z only ---
    f32x4 az[4][2];
#pragma unroll
    for (int r = 0; r < 4; ++r) {
      int ibase = (4 * wr + r) * 16 + quad * 4;
      int cg    = ibase >> 3;
#pragma unroll
      for (int c2 = 0; c2 < 2; ++c2) {
        int jg  = (2 * wc + c2) * 16 + (lane & 15);
        int idx = jg * 128 + ((cg ^ (jg & 15)) << 3) + (ibase & 7);
        s16x4 zv = *(const s16x4*)(Zb + idx);
#pragma unroll
        for (int e = 0; e < 4; ++e) az[r][c2][e] = bf2f((unsigned short)zv[e]);
      }
    }
#pragma unroll
    for (int ks = 0; ks < 4; ++ks) {
      s16x8 aD[4], bZ[2];
#pragma unroll
      for (int r = 0; r < 4; ++r)
        aD[r] = load_frag(Db, (4 * wr + r) * 16, ks, lane);
#pragma unroll
      for (int c2 = 0; c2 < 2; ++c2)
        bZ[c2] = load_frag(Zb, (2 * wc + c2) * 16, ks, lane);
#pragma unroll
      for (int r = 0; r < 4; ++r)
#pragma unroll
        for (int c2 = 0; c2 < 2; ++c2)
          az[r][c2] = __builtin_amdgcn_mfma_f32_16x16x32_bf16(aD[r], bZ[c2], az[r][c2], 0, 0, 0);
    }
    __syncthreads();

    // --- (d) store Z' only ---
#pragma unroll
    for (int r = 0; r < 4; ++r) {
      int ibase = (4 * wr + r) * 16 + quad * 4;
      int cg    = ibase >> 3;
#pragma unroll
      for (int c2 = 0; c2 < 2; ++c2) {
        int jg  = (2 * wc + c2) * 16 + (lane & 15);
        int idx = jg * 128 + ((cg ^ (jg & 15)) << 3) + (ibase & 7);
        s16x4 vz;
#pragma unroll
        for (int e = 0; e < 4; ++e) vz[e] = (short)f2bf(az[r][c2][e]);
        *(s16x4*)(Zb + idx) = vz;
      }
    }
    __syncthreads();
  }

  // ---- traces: tr(GZ) (fp32 anchor in regs), tr(Z), tr(Z^3) ----
  float t_gz = 0.f, t_z = 0.f, t_z3 = 0.f;
  if (bid < NCLS) {
#pragma unroll
    for (int a = 0; a < 8; ++a) {
      s16x4 zv = *(const s16x4*)(Zb + swz_idx(i0 + a, j0));
#pragma unroll
      for (int b = 0; b < 4; ++b) t_gz += accg[a][b] * bf2f((unsigned short)zv[b]);
    }
  } else {
#pragma unroll
    for (int t = 0; t < 8; ++t) {
      int idx4 = tid + 512 * t;
      int flat = idx4 * 4, i = flat >> 7, jj = flat & 127;
      s16x4 zv = *(const s16x4*)(Zb + swz_idx(i, jj));
#pragma unroll
      for (int e = 0; e < 4; ++e) t_gz += ((const float*)&gs[t])[e] * bf2f((unsigned short)zv[e]);
    }
  }
  if (tid < DIM) t_z = bf2f((unsigned short)Zb[swz_idx(tid, tid)]);

  {  // U = Z*Z tile-wise; tr(Z^3) = sum U_ij * Z_ji
    f32x4 u[4][2];
#pragma unroll
    for (int r = 0; r < 4; ++r)
#pragma unroll
      for (int c2 = 0; c2 < 2; ++c2) u[r][c2] = (f32x4)0.f;
#pragma unroll
    for (int ks = 0; ks < 4; ++ks) {
      s16x8 a[4], b[2];
#pragma unroll
      for (int r = 0; r < 4; ++r) a[r] = load_frag(Zb, (4 * wr + r) * 16, ks, lane);
#pragma unroll
      for (int c2 = 0; c2 < 2; ++c2) b[c2] = load_frag(Zb, (2 * wc + c2) * 16, ks, lane);
#pragma unroll
      for (int r = 0; r < 4; ++r)
#pragma unroll
        for (int c2 = 0; c2 < 2; ++c2)
          u[r][c2] = __builtin_amdgcn_mfma_f32_16x16x32_bf16(a[r], b[c2], u[r][c2], 0, 0, 0);
    }
#pragma unroll
    for (int r = 0; r < 4; ++r) {
      int ibase = (4 * wr + r) * 16 + quad * 4;
      int cg    = ibase >> 3;
#pragma unroll
      for (int c2 = 0; c2 < 2; ++c2) {
        int jg  = (2 * wc + c2) * 16 + (lane & 15);
        int idx = jg * 128 + ((cg ^ (jg & 15)) << 3) + (ibase & 7);
        s16x4 zt = *(const s16x4*)(Zb + idx);
#pragma unroll
        for (int e = 0; e < 4; ++e) t_z3 += u[r][c2][e] * bf2f((unsigned short)zt[e]);
      }
    }
  }

  for (int off = 32; off > 0; off >>= 1) {
    t_gz += __shfl_down(t_gz, off, 64);
    t_z  += __shfl_down(t_z,  off, 64);
    t_z3 += __shfl_down(t_z3, off, 64);
  }
  __syncthreads();
  float* red = (float*)Db;             // Db dead after last iter
  if (lane == 0) { red[wv] = t_gz; red[8 + wv] = t_z; red[16 + wv] = t_z3; }
  __syncthreads();

  float nuc_own = 0.f;
  if (tid == 0) {
    float gz = 0.f, z1 = 0.f, z3 = 0.f;
#pragma unroll
    for (int w = 0; w < 8; ++w) { gz += red[w]; z1 += red[8 + w]; z3 += red[16 + w]; }
    float trsq = gz * invs + 0.5f * eps * z1 - 0.125f * eps * eps * z3;
    nuc_own = sqrtf(s) * trsq;
    nuc[bid] = nuc_own;
  }

  if (bid < NCLS) {
    if (tid == 0) flag_set(&nflag[bid]);
    return;
  }

  // ======== block 64: final combine (parallel poll, one flag/lane) ========
  if (tid < NCLS)          flag_wait(&nflag[tid]);
  else if (tid < 2 * NCLS) flag_wait(&ceflag[tid - NCLS]);
  __syncthreads();

  float ce2 = cepart[tid];                       // 512 entries, 512 threads
  float vmx = (tid < NCLS) ? fmaxf(nuc[tid], DELTA_) : 0.f;
  for (int off = 32; off > 0; off >>= 1) {
    vmx += __shfl_down(vmx, off, 64);
    ce2 += __shfl_down(ce2, off, 64);
  }
  if (lane == 0) { red[wv] = vmx; red[8 + wv] = ce2; }
  __syncthreads();
  if (tid == 0) {
    float vs = 0.f, cs = 0.f;
#pragma unroll
    for (int w = 0; w < 8; ++w) { vs += red[w]; cs += red[8 + w]; }
    float ole = (vs - nuc_own) * (LAMBDA_ / (float)N_ROWS);
    out[0] = ole + cs / (float)N_ROWS;
  }
}

extern "C" void kernel_launch(void* const* d_in, const int* in_sizes, int n_in,
                              void* d_out, int out_size, void* d_ws, size_t ws_size,
                              hipStream_t stream) {
  const float* logits = (const float*)d_in[0];   // out  [8192,64]
  const float* feat   = (const float*)d_in[1];   // feat [8192,128]
  const int*   yp     = (const int*)d_in[2];     // y    [8192]

  int*   flags  = (int*)d_ws;                    // 256 ints (208 used)
  float* nuc    = (float*)d_ws + 256;            // 68
  float* cepart = nuc + 68;                      // 512
  float* G      = cepart + 512;                  // 65 x 16384 (Gall = idx 64)

  // Zero the flag region (workspace is poisoned each run; keeps flag
  // semantics independent of harness re-poison timing). Graph-capture-safe.
  hipMemsetAsync(d_ws, 0, 256 * sizeof(int), stream);

  ole_fused<<<NCLS + 1 + NB_CE + NB_BLD, 512, 0, stream>>>(
      feat, yp, logits, G, nuc, cepart, flags, (float*)d_out);
}